// Round 7
// baseline (550.999 us; speedup 1.0000x reference)
//
#include <hip/hip_runtime.h>
#include <math.h>

// Problem constants
constexpr int B_ = 512, S_ = 72, N_ = 5, F_ = 10;
constexpr int H_ = 4, C_ = 32, D_ = 128;
constexpr int L_ = 3, FF_ = 256;
constexpr int K_ = 6, NS_ = 5;
constexpr int G_ = B_ * S_;           // 36864
constexpr float EPS_ = 1e-5f;
constexpr int SP_ = 80;               // S padded to 5*16 for MFMA fragments
constexpr int KP_ = 96;               // PV K-dim padded to 3*32

typedef short bf16x8 __attribute__((ext_vector_type(8)));
typedef float f32x4 __attribute__((ext_vector_type(4)));

__device__ __forceinline__ short f2bf(float f) {
    unsigned int u = __float_as_uint(f);
    u += 0x7FFFu + ((u >> 16) & 1u);      // round-to-nearest-even
    return (short)(u >> 16);
}

// ---------------------------------------------------------------------------
// Kernel 1: fused GAT -> layernorm -> node-mean -> +positional encoding
// One block (128 threads) per group g (= b*S + s). Thread d owns channel d.
// Graph is complete + self loops: for every dst node, incoming srcs = all 5.
// ---------------------------------------------------------------------------
__global__ __launch_bounds__(128) void gat_kernel(
    const float* __restrict__ x,        // (G, N, F)
    const float* __restrict__ gat_w,    // (F, D)
    const float* __restrict__ att_src,  // (D)
    const float* __restrict__ att_dst,  // (D)
    const float* __restrict__ gat_bias, // (D)
    const float* __restrict__ ln_g,     // (D)
    const float* __restrict__ ln_b,     // (D)
    float* __restrict__ t_out)          // (G, D)
{
    const int g = blockIdx.x;
    const int d = threadIdx.x;          // 0..127
    const int s = g % S_;

    __shared__ float xs[N_][F_];
    __shared__ float asrc[N_][H_];
    __shared__ float adst[N_][H_];
    __shared__ float red[N_][2][2];     // [n][wave][sum, sumsq]

    if (d < N_ * F_) xs[d / F_][d % F_] = x[(size_t)g * N_ * F_ + d];
    __syncthreads();

    float wcol[F_];
#pragma unroll
    for (int f = 0; f < F_; ++f) wcol[f] = gat_w[f * D_ + d];
    float hn[N_];
#pragma unroll
    for (int n = 0; n < N_; ++n) {
        float acc = 0.f;
#pragma unroll
        for (int f = 0; f < F_; ++f) acc = fmaf(xs[n][f], wcol[f], acc);
        hn[n] = acc;
    }

    const float ws = att_src[d];
    const float wd = att_dst[d];
    const int head = d >> 5;
#pragma unroll
    for (int n = 0; n < N_; ++n) {
        float ps = hn[n] * ws;
        float pd = hn[n] * wd;
#pragma unroll
        for (int off = 16; off >= 1; off >>= 1) {
            ps += __shfl_xor(ps, off);
            pd += __shfl_xor(pd, off);
        }
        if ((d & 31) == 0) { asrc[n][head] = ps; adst[n][head] = pd; }
    }
    __syncthreads();

    float a_s[N_];
#pragma unroll
    for (int m = 0; m < N_; ++m) a_s[m] = asrc[m][head];

    float y[N_];
#pragma unroll
    for (int n = 0; n < N_; ++n) {
        const float ad = adst[n][head];
        float e[N_];
        float mx = -1e30f;
#pragma unroll
        for (int m = 0; m < N_; ++m) {
            float v = a_s[m] + ad;
            v = v > 0.f ? v : 0.2f * v;       // leaky_relu(0.2)
            e[m] = v;
            mx = fmaxf(mx, v);
        }
        float den = 0.f;
#pragma unroll
        for (int m = 0; m < N_; ++m) { e[m] = __expf(e[m] - mx); den += e[m]; }
        const float inv = 1.f / den;
        float agg = 0.f;
#pragma unroll
        for (int m = 0; m < N_; ++m) agg = fmaf(e[m] * inv, hn[m], agg);
        y[n] = agg + gat_bias[d];
    }

    const int wave = d >> 6;
#pragma unroll
    for (int n = 0; n < N_; ++n) {
        float sm = y[n];
        float sq = y[n] * y[n];
#pragma unroll
        for (int off = 32; off >= 1; off >>= 1) {
            sm += __shfl_xor(sm, off);
            sq += __shfl_xor(sq, off);
        }
        if ((d & 63) == 0) { red[n][wave][0] = sm; red[n][wave][1] = sq; }
    }
    __syncthreads();

    const float gg = ln_g[d];
    const float bb = ln_b[d];
    float tacc = 0.f;
#pragma unroll
    for (int n = 0; n < N_; ++n) {
        const float sm = red[n][0][0] + red[n][1][0];
        const float sq = red[n][0][1] + red[n][1][1];
        const float mean = sm * (1.f / D_);
        const float var = sq * (1.f / D_) - mean * mean;
        const float rstd = rsqrtf(var + EPS_);
        tacc += (y[n] - mean) * rstd * gg + bb;
    }
    tacc *= (1.f / N_);

    const float expo = -(float)(d & ~1) * (9.210340371976184f / 128.f);
    const float ang = (float)s * expf(expo);
    const float pe = (d & 1) ? cosf(ang) : sinf(ang);

    t_out[(size_t)g * D_ + d] = tacc + pe;
}

// ---------------------------------------------------------------------------
// Kernel 2: bf16-MFMA linear: out[r,c] = act(sum_k A[r,k]*W[c,k] + bias[c])
// A fp32 (Rows, K), W fp32 (Cout, K) row-major. fp32->bf16 fused into LDS
// staging. Block tile 64x64, 4 waves (2x2), wave tile 32x32 (2x2 fragments of
// mfma_f32_16x16x32_bf16), BK=64.
// LDS tiles [64][64] bf16 = 128B rows; 16B-slot XOR swizzle (slot ^= row&7)
// on write AND read -> bank-balanced (guide G4 / T2).
// ---------------------------------------------------------------------------
__global__ __launch_bounds__(256) void linear_mfma_kernel(
    const float* __restrict__ A, const float* __restrict__ W,
    const float* __restrict__ bias, float* __restrict__ out,
    int K, int Cout, int relu)
{
    __shared__ short As[64 * 64];   // [row][k], 8KB
    __shared__ short Ws[64 * 64];   // [col][k], 8KB

    const int tid = threadIdx.x;
    const int lane = tid & 63;
    const int wid = tid >> 6;       // 0..3
    const int wr = wid >> 1;        // wave row (0/1)
    const int wc = wid & 1;         // wave col (0/1)
    const int r0 = blockIdx.x * 64;
    const int c0 = blockIdx.y * 64;

    // staging coords: thread covers 8 k-values (one 16B bf16 slot) of one row
    const int st_row = tid >> 3;    // 0..31 (+32 on second iter)
    const int st_slot = tid & 7;    // k-slot (8 bf16 = 16B)

    f32x4 acc[2][2] = {};

    for (int kk = 0; kk < K; kk += 64) {
        if (kk) __syncthreads();
#pragma unroll
        for (int it = 0; it < 2; ++it) {
            const int row = st_row + it * 32;
            const int gk = kk + st_slot * 8;
            const int pslot = st_slot ^ (row & 7);
            // A tile
            {
                const float* src = &A[(size_t)(r0 + row) * K + gk];
                const float4 a0 = *reinterpret_cast<const float4*>(src);
                const float4 a1 = *reinterpret_cast<const float4*>(src + 4);
                bf16x8 h;
                h[0] = f2bf(a0.x); h[1] = f2bf(a0.y);
                h[2] = f2bf(a0.z); h[3] = f2bf(a0.w);
                h[4] = f2bf(a1.x); h[5] = f2bf(a1.y);
                h[6] = f2bf(a1.z); h[7] = f2bf(a1.w);
                *reinterpret_cast<bf16x8*>(&As[row * 64 + pslot * 8]) = h;
            }
            // W tile (rows of W = output cols)
            {
                const float* src = &W[(size_t)(c0 + row) * K + gk];
                const float4 w0 = *reinterpret_cast<const float4*>(src);
                const float4 w1 = *reinterpret_cast<const float4*>(src + 4);
                bf16x8 h;
                h[0] = f2bf(w0.x); h[1] = f2bf(w0.y);
                h[2] = f2bf(w0.z); h[3] = f2bf(w0.w);
                h[4] = f2bf(w1.x); h[5] = f2bf(w1.y);
                h[6] = f2bf(w1.z); h[7] = f2bf(w1.w);
                *reinterpret_cast<bf16x8*>(&Ws[row * 64 + pslot * 8]) = h;
            }
        }
        __syncthreads();

#pragma unroll
        for (int j = 0; j < 2; ++j) {          // inner K-step (32 each)
            bf16x8 aF[2], bF[2];
#pragma unroll
            for (int m = 0; m < 2; ++m) {
                const int row = wr * 32 + m * 16 + (lane & 15);
                const int slot = j * 4 + (lane >> 4);
                const int pslot = slot ^ (row & 7);
                aF[m] = *reinterpret_cast<const bf16x8*>(&As[row * 64 + pslot * 8]);
            }
#pragma unroll
            for (int n = 0; n < 2; ++n) {
                const int col = wc * 32 + n * 16 + (lane & 15);
                const int slot = j * 4 + (lane >> 4);
                const int pslot = slot ^ (col & 7);
                bF[n] = *reinterpret_cast<const bf16x8*>(&Ws[col * 64 + pslot * 8]);
            }
#pragma unroll
            for (int m = 0; m < 2; ++m)
#pragma unroll
                for (int n = 0; n < 2; ++n)
                    acc[m][n] = __builtin_amdgcn_mfma_f32_16x16x32_bf16(
                        aF[m], bF[n], acc[m][n], 0, 0, 0);
        }
    }

    // epilogue: C/D layout col=lane&15, row=(lane>>4)*4+reg
#pragma unroll
    for (int m = 0; m < 2; ++m) {
#pragma unroll
        for (int n = 0; n < 2; ++n) {
            const int col = c0 + wc * 32 + n * 16 + (lane & 15);
            const float bv = bias[col];
#pragma unroll
            for (int j = 0; j < 4; ++j) {
                const int row = r0 + wr * 32 + m * 16 + (lane >> 4) * 4 + j;
                float v = acc[m][n][j] + bv;
                if (relu) v = fmaxf(v, 0.f);
                out[(size_t)row * Cout + col] = v;
            }
        }
    }
}

// ---------------------------------------------------------------------------
// Kernel 3: bf16-MFMA attention for one (b, head). qkv layout (G,384).
// Scores = Q*K^T uses the SAME fragment pattern as linear (A=Q [row][k],
// K staged like W [col][k]). Softmax in-register on C/D fragments (16-lane
// shfl groups). PV = P*V with W=V^T (transpose-staged), K-dim padded to 96.
// All pad regions zeroed; 1/den applied at the PV epilogue.
// ---------------------------------------------------------------------------
__global__ __launch_bounds__(256) void attn_mfma_kernel(
    const float* __restrict__ qkv, float* __restrict__ o)
{
    const int bh = blockIdx.x;
    const int b = bh >> 2;
    const int h = bh & 3;

    __shared__ short Qs[SP_ * 32];    // [i][c] bf16 (q*scale); rows 72..79 = 0
    __shared__ short Ks[SP_ * 32];    // [j][c] bf16; rows 72..79 = 0
    __shared__ short VT[32 * KP_];    // [c][j] bf16; j 72..95 = 0
    __shared__ short Pb[SP_ * KP_];   // [i][j] bf16 exp(s-mx); j 72..95 = 0

    const int tid = threadIdx.x;
    const int lane = tid & 63;
    const int wid = tid >> 6;         // 0..3
    const int g = lane >> 4;          // 0..3
    const int c16 = lane & 15;

    const float scale = 0.17677669529663687f;  // 1/sqrt(32)

    // --- stage Q*scale, K as [row][c]; V transposed into VT[c][j]
    for (int idx = tid; idx < S_ * 8; idx += 256) {
        const int i = idx >> 3;
        const int c4 = (idx & 7) * 4;
        const size_t base = ((size_t)(b * S_ + i)) * 384 + h * 32 + c4;
        const float4 q = *reinterpret_cast<const float4*>(&qkv[base]);
        const float4 k = *reinterpret_cast<const float4*>(&qkv[base + 128]);
        const float4 v = *reinterpret_cast<const float4*>(&qkv[base + 256]);
        short4 qh, kh;
        qh.x = f2bf(q.x * scale); qh.y = f2bf(q.y * scale);
        qh.z = f2bf(q.z * scale); qh.w = f2bf(q.w * scale);
        kh.x = f2bf(k.x); kh.y = f2bf(k.y);
        kh.z = f2bf(k.z); kh.w = f2bf(k.w);
        *reinterpret_cast<short4*>(&Qs[i * 32 + c4]) = qh;
        *reinterpret_cast<short4*>(&Ks[i * 32 + c4]) = kh;
        VT[(c4 + 0) * KP_ + i] = f2bf(v.x);
        VT[(c4 + 1) * KP_ + i] = f2bf(v.y);
        VT[(c4 + 2) * KP_ + i] = f2bf(v.z);
        VT[(c4 + 3) * KP_ + i] = f2bf(v.w);
    }
    // zero pads (no NaN may reach a stored row)
    for (int idx = tid; idx < 8 * 32; idx += 256) {   // Q/K rows 72..79
        Qs[S_ * 32 + idx] = 0;
        Ks[S_ * 32 + idx] = 0;
    }
    for (int idx = tid; idx < 32 * 24; idx += 256) {  // VT j = 72..95
        VT[(idx / 24) * KP_ + 72 + idx % 24] = 0;
    }
    for (int idx = tid; idx < SP_ * 24; idx += 256) { // Pb j = 72..95
        Pb[(idx / 24) * KP_ + 72 + idx % 24] = 0;
    }
    __syncthreads();

    // --- scores + in-register softmax. Row-fragment split: wave w owns
    // m = w (and wave 0 also m = 4). One k-step (C=32).
    float invr[2][4];
#pragma unroll
    for (int mi = 0; mi < 2; ++mi) {
        const int m = wid + 4 * mi;
        if (m <= 4) {
            const int rowb = m * 16;
            const bf16x8 aF = *reinterpret_cast<const bf16x8*>(
                &Qs[(rowb + c16) * 32 + 8 * g]);
            f32x4 sc[5];
#pragma unroll
            for (int n = 0; n < 5; ++n) {
                const bf16x8 bF = *reinterpret_cast<const bf16x8*>(
                    &Ks[(n * 16 + c16) * 32 + 8 * g]);
                f32x4 z = {};
                sc[n] = __builtin_amdgcn_mfma_f32_16x16x32_bf16(aF, bF, z, 0, 0, 0);
            }
            // softmax: lane's rows are rowb + 4*g + j; cols n*16 + c16
#pragma unroll
            for (int j = 0; j < 4; ++j) {
                float mx = -1e30f;
#pragma unroll
                for (int n = 0; n < 5; ++n) {
                    const int col = n * 16 + c16;
                    if (col < S_) mx = fmaxf(mx, sc[n][j]);
                }
                mx = fmaxf(mx, __shfl_xor(mx, 1));
                mx = fmaxf(mx, __shfl_xor(mx, 2));
                mx = fmaxf(mx, __shfl_xor(mx, 4));
                mx = fmaxf(mx, __shfl_xor(mx, 8));
                float den = 0.f;
                float p[5];
#pragma unroll
                for (int n = 0; n < 5; ++n) {
                    const int col = n * 16 + c16;
                    p[n] = (col < S_) ? __expf(sc[n][j] - mx) : 0.f;
                    den += p[n];
                }
                den += __shfl_xor(den, 1);
                den += __shfl_xor(den, 2);
                den += __shfl_xor(den, 4);
                den += __shfl_xor(den, 8);
                invr[mi][j] = 1.f / den;
                const int row = rowb + 4 * g + j;
#pragma unroll
                for (int n = 0; n < 5; ++n)
                    Pb[row * KP_ + n * 16 + c16] = f2bf(p[n]);
            }
        }
    }
    __syncthreads();

    // --- PV: out[i][c] = (sum_j Pb[i][j] * V[j][c]) * invr[i]
#pragma unroll
    for (int mi = 0; mi < 2; ++mi) {
        const int m = wid + 4 * mi;
        if (m <= 4) {
            const int rowb = m * 16;
            f32x4 accO[2] = {};
#pragma unroll
            for (int kk = 0; kk < 3; ++kk) {
                const bf16x8 aF = *reinterpret_cast<const bf16x8*>(
                    &Pb[(rowb + c16) * KP_ + kk * 32 + 8 * g]);
#pragma unroll
                for (int n2 = 0; n2 < 2; ++n2) {
                    const bf16x8 bF = *reinterpret_cast<const bf16x8*>(
                        &VT[(n2 * 16 + c16) * KP_ + kk * 32 + 8 * g]);
                    accO[n2] = __builtin_amdgcn_mfma_f32_16x16x32_bf16(
                        aF, bF, accO[n2], 0, 0, 0);
                }
            }
#pragma unroll
            for (int j = 0; j < 4; ++j) {
                const int row = rowb + 4 * g + j;
                if (row < S_) {
                    const float inv = invr[mi][j];
#pragma unroll
                    for (int n2 = 0; n2 < 2; ++n2) {
                        o[((size_t)(b * S_ + row)) * D_ + h * 32 + n2 * 16 + c16]
                            = accO[n2][j] * inv;
                    }
                }
            }
        }
    }
}

// ---------------------------------------------------------------------------
// Kernel 4: residual add + layernorm (in place on t). 2 rows per 256-thr block.
// ---------------------------------------------------------------------------
__global__ __launch_bounds__(256) void add_ln_kernel(
    float* __restrict__ t, const float* __restrict__ r,
    const float* __restrict__ g, const float* __restrict__ b)
{
    const int local = threadIdx.x >> 7;             // 0/1: which row
    const int row = blockIdx.x * 2 + local;
    const int d = threadIdx.x & 127;
    const size_t idx = (size_t)row * D_ + d;

    const float v = t[idx] + r[idx];

    float sm = v, sq = v * v;
#pragma unroll
    for (int off = 32; off >= 1; off >>= 1) {
        sm += __shfl_xor(sm, off);
        sq += __shfl_xor(sq, off);
    }
    __shared__ float red[4][2];
    const int wave = threadIdx.x >> 6;
    if ((threadIdx.x & 63) == 0) { red[wave][0] = sm; red[wave][1] = sq; }
    __syncthreads();

    const int w0 = local * 2;
    const float s1 = red[w0][0] + red[w0 + 1][0];
    const float s2 = red[w0][1] + red[w0 + 1][1];
    const float mean = s1 * (1.f / D_);
    const float var = s2 * (1.f / D_) - mean * mean;
    const float rstd = rsqrtf(var + EPS_);
    t[idx] = (v - mean) * rstd * g[d] + b[d];
}

// ---------------------------------------------------------------------------
// Kernel 5: head MLP. One 64-thread block per (k, b).
// ---------------------------------------------------------------------------
__global__ __launch_bounds__(64) void head_kernel(
    const float* __restrict__ t, const float* __restrict__ h1_w,
    const float* __restrict__ h1_b, const float* __restrict__ h2_w,
    const float* __restrict__ h2_b, float* __restrict__ out)
{
    const int kb = blockIdx.x;
    const int k = kb / B_;
    const int b = kb - k * B_;
    const int o = threadIdx.x;  // 0..63

    const float* xr = &t[((size_t)(b * S_ + S_ - 1)) * D_];
    const float* wr = &h1_w[((size_t)k * 64 + o) * D_];
    float acc = h1_b[k * 64 + o];
#pragma unroll 8
    for (int d = 0; d < D_; ++d) acc = fmaf(xr[d], wr[d], acc);
    const float h1v = fmaxf(acc, 0.f);

#pragma unroll
    for (int p = 0; p < NS_; ++p) {
        float partial = h1v * h2_w[((size_t)k * NS_ + p) * 64 + o];
#pragma unroll
        for (int off = 32; off >= 1; off >>= 1) partial += __shfl_xor(partial, off);
        if (o == 0) out[((size_t)k * B_ + b) * NS_ + p] = partial + h2_b[k * NS_ + p];
    }
}

// ---------------------------------------------------------------------------
extern "C" void kernel_launch(void* const* d_in, const int* in_sizes, int n_in,
                              void* d_out, int out_size, void* d_ws, size_t ws_size,
                              hipStream_t stream) {
    const float* x        = (const float*)d_in[0];
    // d_in[1] = edge_index: graph is complete + self loops; structure hardcoded
    const float* gat_w    = (const float*)d_in[2];
    const float* att_src  = (const float*)d_in[3];
    const float* att_dst  = (const float*)d_in[4];
    const float* gat_bias = (const float*)d_in[5];
    const float* gat_ln_g = (const float*)d_in[6];
    const float* gat_ln_b = (const float*)d_in[7];
    const float* qkv_w    = (const float*)d_in[8];
    const float* qkv_b    = (const float*)d_in[9];
    const float* out_w    = (const float*)d_in[10];
    const float* out_b    = (const float*)d_in[11];
    const float* ln1_g    = (const float*)d_in[12];
    const float* ln1_b    = (const float*)d_in[13];
    const float* ff1_w    = (const float*)d_in[14];
    const float* ff1_b    = (const float*)d_in[15];
    const float* ff2_w    = (const float*)d_in[16];
    const float* ff2_b    = (const float*)d_in[17];
    const float* ln2_g    = (const float*)d_in[18];
    const float* ln2_b    = (const float*)d_in[19];
    const float* h1_w     = (const float*)d_in[20];
    const float* h1_b     = (const float*)d_in[21];
    const float* h2_w     = (const float*)d_in[22];
    const float* h2_b     = (const float*)d_in[23];
    float* out = (float*)d_out;

    // scratch layout (floats): t | qkv | fbuf(attn-out alias) | proj
    float* ws   = (float*)d_ws;
    float* t    = ws;
    float* qkv  = t + (size_t)G_ * D_;          // G*384
    float* fbuf = qkv + (size_t)G_ * 384;       // G*256 (attn out uses G*128 of it)
    float* proj = fbuf + (size_t)G_ * FF_;      // G*128

    gat_kernel<<<G_, 128, 0, stream>>>(x, gat_w, att_src, att_dst,
                                       gat_bias, gat_ln_g, gat_ln_b, t);

    for (int l = 0; l < L_; ++l) {
        linear_mfma_kernel<<<dim3(G_ / 64, 384 / 64), 256, 0, stream>>>(
            t, qkv_w + (size_t)l * 384 * D_, qkv_b + (size_t)l * 384, qkv,
            D_, 384, 0);
        attn_mfma_kernel<<<B_ * H_, 256, 0, stream>>>(qkv, fbuf);
        linear_mfma_kernel<<<dim3(G_ / 64, D_ / 64), 256, 0, stream>>>(
            fbuf, out_w + (size_t)l * D_ * D_, out_b + (size_t)l * D_, proj,
            D_, D_, 0);
        add_ln_kernel<<<G_ / 2, 256, 0, stream>>>(t, proj,
                                                  ln1_g + l * D_, ln1_b + l * D_);
        linear_mfma_kernel<<<dim3(G_ / 64, FF_ / 64), 256, 0, stream>>>(
            t, ff1_w + (size_t)l * FF_ * D_, ff1_b + (size_t)l * FF_, fbuf,
            D_, FF_, 1);
        linear_mfma_kernel<<<dim3(G_ / 64, D_ / 64), 256, 0, stream>>>(
            fbuf, ff2_w + (size_t)l * D_ * FF_, ff2_b + (size_t)l * D_, proj,
            FF_, D_, 0);
        add_ln_kernel<<<G_ / 2, 256, 0, stream>>>(t, proj,
                                                  ln2_g + l * D_, ln2_b + l * D_);
    }

    head_kernel<<<K_ * B_, 64, 0, stream>>>(t, h1_w, h1_b, h2_w, h2_b, out);
}

// Round 9
// 493.468 us; speedup vs baseline: 1.1166x; 1.1166x over previous
//
#include <hip/hip_runtime.h>
#include <math.h>

// Problem constants
constexpr int B_ = 512, S_ = 72, N_ = 5, F_ = 10;
constexpr int H_ = 4, C_ = 32, D_ = 128;
constexpr int L_ = 3, FF_ = 256;
constexpr int K_ = 6, NS_ = 5;
constexpr int G_ = B_ * S_;           // 36864
constexpr float EPS_ = 1e-5f;
constexpr int SP_ = 80;               // S padded to 5*16 for MFMA fragments
constexpr int KP_ = 96;               // PV K-dim padded to 3*32

typedef short bf16x8 __attribute__((ext_vector_type(8)));
typedef float f32x4 __attribute__((ext_vector_type(4)));

__device__ __forceinline__ short f2bf(float f) {
    unsigned int u = __float_as_uint(f);
    u += 0x7FFFu + ((u >> 16) & 1u);      // round-to-nearest-even
    return (short)(u >> 16);
}

// ---------------------------------------------------------------------------
// Kernel 0: positional-encoding table (S x D), computed ONCE per launch.
// Removes 4.7M redundant sinf/cosf/expf calls from gat_kernel (512x reuse).
// ---------------------------------------------------------------------------
__global__ __launch_bounds__(128) void pe_kernel(float* __restrict__ pe)
{
    const int s = blockIdx.x;           // 0..71
    const int d = threadIdx.x;          // 0..127
    const float expo = -(float)(d & ~1) * (9.210340371976184f / 128.f);
    const float ang = (float)s * expf(expo);
    pe[s * D_ + d] = (d & 1) ? cosf(ang) : sinf(ang);
}

// ---------------------------------------------------------------------------
// Kernel 1: fused GAT -> layernorm -> node-mean -> +pe (table lookup).
// ---------------------------------------------------------------------------
__global__ __launch_bounds__(128) void gat_kernel(
    const float* __restrict__ x,        // (G, N, F)
    const float* __restrict__ gat_w,    // (F, D)
    const float* __restrict__ att_src,  // (D)
    const float* __restrict__ att_dst,  // (D)
    const float* __restrict__ gat_bias, // (D)
    const float* __restrict__ ln_g,     // (D)
    const float* __restrict__ ln_b,     // (D)
    const float* __restrict__ pe,       // (S, D) precomputed table
    float* __restrict__ t_out)          // (G, D)
{
    const int g = blockIdx.x;
    const int d = threadIdx.x;          // 0..127
    const int s = g % S_;

    __shared__ float xs[N_][F_];
    __shared__ float asrc[N_][H_];
    __shared__ float adst[N_][H_];
    __shared__ float red[N_][2][2];     // [n][wave][sum, sumsq]

    if (d < N_ * F_) xs[d / F_][d % F_] = x[(size_t)g * N_ * F_ + d];
    __syncthreads();

    float wcol[F_];
#pragma unroll
    for (int f = 0; f < F_; ++f) wcol[f] = gat_w[f * D_ + d];
    float hn[N_];
#pragma unroll
    for (int n = 0; n < N_; ++n) {
        float acc = 0.f;
#pragma unroll
        for (int f = 0; f < F_; ++f) acc = fmaf(xs[n][f], wcol[f], acc);
        hn[n] = acc;
    }

    const float ws = att_src[d];
    const float wd = att_dst[d];
    const int head = d >> 5;
#pragma unroll
    for (int n = 0; n < N_; ++n) {
        float ps = hn[n] * ws;
        float pd = hn[n] * wd;
#pragma unroll
        for (int off = 16; off >= 1; off >>= 1) {
            ps += __shfl_xor(ps, off);
            pd += __shfl_xor(pd, off);
        }
        if ((d & 31) == 0) { asrc[n][head] = ps; adst[n][head] = pd; }
    }
    __syncthreads();

    float a_s[N_];
#pragma unroll
    for (int m = 0; m < N_; ++m) a_s[m] = asrc[m][head];

    float y[N_];
#pragma unroll
    for (int n = 0; n < N_; ++n) {
        const float ad = adst[n][head];
        float e[N_];
        float mx = -1e30f;
#pragma unroll
        for (int m = 0; m < N_; ++m) {
            float v = a_s[m] + ad;
            v = v > 0.f ? v : 0.2f * v;       // leaky_relu(0.2)
            e[m] = v;
            mx = fmaxf(mx, v);
        }
        float den = 0.f;
#pragma unroll
        for (int m = 0; m < N_; ++m) { e[m] = __expf(e[m] - mx); den += e[m]; }
        const float inv = 1.f / den;
        float agg = 0.f;
#pragma unroll
        for (int m = 0; m < N_; ++m) agg = fmaf(e[m] * inv, hn[m], agg);
        y[n] = agg + gat_bias[d];
    }

    const int wave = d >> 6;
#pragma unroll
    for (int n = 0; n < N_; ++n) {
        float sm = y[n];
        float sq = y[n] * y[n];
#pragma unroll
        for (int off = 32; off >= 1; off >>= 1) {
            sm += __shfl_xor(sm, off);
            sq += __shfl_xor(sq, off);
        }
        if ((d & 63) == 0) { red[n][wave][0] = sm; red[n][wave][1] = sq; }
    }
    __syncthreads();

    const float gg = ln_g[d];
    const float bb = ln_b[d];
    float tacc = 0.f;
#pragma unroll
    for (int n = 0; n < N_; ++n) {
        const float sm = red[n][0][0] + red[n][1][0];
        const float sq = red[n][0][1] + red[n][1][1];
        const float mean = sm * (1.f / D_);
        const float var = sq * (1.f / D_) - mean * mean;
        const float rstd = rsqrtf(var + EPS_);
        tacc += (y[n] - mean) * rstd * gg + bb;
    }
    tacc *= (1.f / N_);

    t_out[(size_t)g * D_ + d] = tacc + pe[s * D_ + d];
}

// ---------------------------------------------------------------------------
// Kernel 2: bf16-MFMA linear (HW-validated r7): out = act(A*W^T + bias).
// Block tile 64x64, 4 waves (2x2), BK=64, XOR-swizzled LDS (write+read).
// ---------------------------------------------------------------------------
__global__ __launch_bounds__(256) void linear_mfma_kernel(
    const float* __restrict__ A, const float* __restrict__ W,
    const float* __restrict__ bias, float* __restrict__ out,
    int K, int Cout, int relu)
{
    __shared__ short As[64 * 64];   // [row][k], 8KB
    __shared__ short Ws[64 * 64];   // [col][k], 8KB

    const int tid = threadIdx.x;
    const int lane = tid & 63;
    const int wid = tid >> 6;       // 0..3
    const int wr = wid >> 1;        // wave row (0/1)
    const int wc = wid & 1;         // wave col (0/1)
    const int r0 = blockIdx.x * 64;
    const int c0 = blockIdx.y * 64;

    const int st_row = tid >> 3;    // 0..31 (+32 on second iter)
    const int st_slot = tid & 7;    // k-slot (8 bf16 = 16B)

    f32x4 acc[2][2] = {};

    for (int kk = 0; kk < K; kk += 64) {
        if (kk) __syncthreads();
#pragma unroll
        for (int it = 0; it < 2; ++it) {
            const int row = st_row + it * 32;
            const int gk = kk + st_slot * 8;
            const int pslot = st_slot ^ (row & 7);
            {
                const float* src = &A[(size_t)(r0 + row) * K + gk];
                const float4 a0 = *reinterpret_cast<const float4*>(src);
                const float4 a1 = *reinterpret_cast<const float4*>(src + 4);
                bf16x8 h;
                h[0] = f2bf(a0.x); h[1] = f2bf(a0.y);
                h[2] = f2bf(a0.z); h[3] = f2bf(a0.w);
                h[4] = f2bf(a1.x); h[5] = f2bf(a1.y);
                h[6] = f2bf(a1.z); h[7] = f2bf(a1.w);
                *reinterpret_cast<bf16x8*>(&As[row * 64 + pslot * 8]) = h;
            }
            {
                const float* src = &W[(size_t)(c0 + row) * K + gk];
                const float4 w0 = *reinterpret_cast<const float4*>(src);
                const float4 w1 = *reinterpret_cast<const float4*>(src + 4);
                bf16x8 h;
                h[0] = f2bf(w0.x); h[1] = f2bf(w0.y);
                h[2] = f2bf(w0.z); h[3] = f2bf(w0.w);
                h[4] = f2bf(w1.x); h[5] = f2bf(w1.y);
                h[6] = f2bf(w1.z); h[7] = f2bf(w1.w);
                *reinterpret_cast<bf16x8*>(&Ws[row * 64 + pslot * 8]) = h;
            }
        }
        __syncthreads();

#pragma unroll
        for (int j = 0; j < 2; ++j) {
            bf16x8 aF[2], bF[2];
#pragma unroll
            for (int m = 0; m < 2; ++m) {
                const int row = wr * 32 + m * 16 + (lane & 15);
                const int slot = j * 4 + (lane >> 4);
                const int pslot = slot ^ (row & 7);
                aF[m] = *reinterpret_cast<const bf16x8*>(&As[row * 64 + pslot * 8]);
            }
#pragma unroll
            for (int n = 0; n < 2; ++n) {
                const int col = wc * 32 + n * 16 + (lane & 15);
                const int slot = j * 4 + (lane >> 4);
                const int pslot = slot ^ (col & 7);
                bF[n] = *reinterpret_cast<const bf16x8*>(&Ws[col * 64 + pslot * 8]);
            }
#pragma unroll
            for (int m = 0; m < 2; ++m)
#pragma unroll
                for (int n = 0; n < 2; ++n)
                    acc[m][n] = __builtin_amdgcn_mfma_f32_16x16x32_bf16(
                        aF[m], bF[n], acc[m][n], 0, 0, 0);
        }
    }

#pragma unroll
    for (int m = 0; m < 2; ++m) {
#pragma unroll
        for (int n = 0; n < 2; ++n) {
            const int col = c0 + wc * 32 + n * 16 + (lane & 15);
            const float bv = bias[col];
#pragma unroll
            for (int j = 0; j < 4; ++j) {
                const int row = r0 + wr * 32 + m * 16 + (lane >> 4) * 4 + j;
                float v = acc[m][n][j] + bv;
                if (relu) v = fmaxf(v, 0.f);
                out[(size_t)row * Cout + col] = v;
            }
        }
    }
}

// ---------------------------------------------------------------------------
// Kernel 2b: bf16-MFMA linear (Cout=128) fused with residual-add + LayerNorm:
//   t[r,:] = LN(t[r,:] + A[r]*W^T + bias) * g + b     (in place on t)
// Block tile 64 rows x 128 cols => block owns ENTIRE output rows, so row
// stats reduce locally: 16-lane shfl (as attn softmax) + cross-wave LDS.
// Same staging/swizzle/fragment code as linear_mfma_kernel (HW-validated).
// Waves 2x2: wave tile 32 rows x 64 cols (2 m x 4 n fragments).
// ---------------------------------------------------------------------------
__global__ __launch_bounds__(256) void linear_ln_kernel(
    const float* __restrict__ A, const float* __restrict__ W,
    const float* __restrict__ bias, float* __restrict__ t,
    const float* __restrict__ lng, const float* __restrict__ lnb,
    int K)
{
    __shared__ short As[64 * 64];    // 8KB
    __shared__ short Ws2[128 * 64];  // 16KB
    __shared__ float red[64][2][2];  // [row][wc][sum,sumsq], 1KB

    const int tid = threadIdx.x;
    const int lane = tid & 63;
    const int wid = tid >> 6;       // 0..3
    const int wr = wid >> 1;        // 0/1: rows 32*wr..
    const int wc = wid & 1;         // 0/1: cols 64*wc..
    const int c16 = lane & 15;
    const int grp = lane >> 4;      // 0..3
    const int r0 = blockIdx.x * 64;

    const int st_row = tid >> 3;    // 0..31
    const int st_slot = tid & 7;

    f32x4 acc[2][4] = {};

    for (int kk = 0; kk < K; kk += 64) {
        if (kk) __syncthreads();
        // A tile: 64 rows x 64 k
#pragma unroll
        for (int it = 0; it < 2; ++it) {
            const int row = st_row + it * 32;
            const int gk = kk + st_slot * 8;
            const int pslot = st_slot ^ (row & 7);
            const float* src = &A[(size_t)(r0 + row) * K + gk];
            const float4 a0 = *reinterpret_cast<const float4*>(src);
            const float4 a1 = *reinterpret_cast<const float4*>(src + 4);
            bf16x8 h;
            h[0] = f2bf(a0.x); h[1] = f2bf(a0.y);
            h[2] = f2bf(a0.z); h[3] = f2bf(a0.w);
            h[4] = f2bf(a1.x); h[5] = f2bf(a1.y);
            h[6] = f2bf(a1.z); h[7] = f2bf(a1.w);
            *reinterpret_cast<bf16x8*>(&As[row * 64 + pslot * 8]) = h;
        }
        // W tile: 128 cols x 64 k
#pragma unroll
        for (int it = 0; it < 4; ++it) {
            const int row = st_row + it * 32;
            const int gk = kk + st_slot * 8;
            const int pslot = st_slot ^ (row & 7);
            const float* src = &W[(size_t)row * K + gk];
            const float4 w0 = *reinterpret_cast<const float4*>(src);
            const float4 w1 = *reinterpret_cast<const float4*>(src + 4);
            bf16x8 h;
            h[0] = f2bf(w0.x); h[1] = f2bf(w0.y);
            h[2] = f2bf(w0.z); h[3] = f2bf(w0.w);
            h[4] = f2bf(w1.x); h[5] = f2bf(w1.y);
            h[6] = f2bf(w1.z); h[7] = f2bf(w1.w);
            *reinterpret_cast<bf16x8*>(&Ws2[row * 64 + pslot * 8]) = h;
        }
        __syncthreads();

#pragma unroll
        for (int j = 0; j < 2; ++j) {
            bf16x8 aF[2], bF[4];
#pragma unroll
            for (int m = 0; m < 2; ++m) {
                const int row = wr * 32 + m * 16 + c16;
                const int slot = j * 4 + grp;
                const int pslot = slot ^ (row & 7);
                aF[m] = *reinterpret_cast<const bf16x8*>(&As[row * 64 + pslot * 8]);
            }
#pragma unroll
            for (int n = 0; n < 4; ++n) {
                const int col = wc * 64 + n * 16 + c16;
                const int slot = j * 4 + grp;
                const int pslot = slot ^ (col & 7);
                bF[n] = *reinterpret_cast<const bf16x8*>(&Ws2[col * 64 + pslot * 8]);
            }
#pragma unroll
            for (int m = 0; m < 2; ++m)
#pragma unroll
                for (int n = 0; n < 4; ++n)
                    acc[m][n] = __builtin_amdgcn_mfma_f32_16x16x32_bf16(
                        aF[m], bF[n], acc[m][n], 0, 0, 0);
        }
    }

    // --- epilogue: v = acc + bias + t (residual); row LN; write t in place.
    // Thread's rows: wr*32 + m*16 + 4*grp + j; cols: wc*64 + n*16 + c16.
#pragma unroll
    for (int m = 0; m < 2; ++m) {
#pragma unroll
        for (int j = 0; j < 4; ++j) {
            const int row = wr * 32 + m * 16 + 4 * grp + j;
            float sm = 0.f, sq = 0.f;
#pragma unroll
            for (int n = 0; n < 4; ++n) {
                const int col = wc * 64 + n * 16 + c16;
                float v = acc[m][n][j] + bias[col]
                        + t[(size_t)(r0 + row) * D_ + col];
                acc[m][n][j] = v;           // keep for the write phase
                sm += v;
                sq += v * v;
            }
#pragma unroll
            for (int off = 8; off >= 1; off >>= 1) {   // reduce 16 lanes
                sm += __shfl_xor(sm, off);
                sq += __shfl_xor(sq, off);
            }
            if (c16 == 0) { red[row][wc][0] = sm; red[row][wc][1] = sq; }
        }
    }
    __syncthreads();

#pragma unroll
    for (int m = 0; m < 2; ++m) {
#pragma unroll
        for (int j = 0; j < 4; ++j) {
            const int row = wr * 32 + m * 16 + 4 * grp + j;
            const float sm = red[row][0][0] + red[row][1][0];
            const float sq = red[row][0][1] + red[row][1][1];
            const float mean = sm * (1.f / D_);
            const float var = sq * (1.f / D_) - mean * mean;
            const float rstd = rsqrtf(var + EPS_);
#pragma unroll
            for (int n = 0; n < 4; ++n) {
                const int col = wc * 64 + n * 16 + c16;
                t[(size_t)(r0 + row) * D_ + col] =
                    (acc[m][n][j] - mean) * rstd * lng[col] + lnb[col];
            }
        }
    }
}

// ---------------------------------------------------------------------------
// Kernel 3: bf16-MFMA attention (HW-validated r7).
// ---------------------------------------------------------------------------
__global__ __launch_bounds__(256) void attn_mfma_kernel(
    const float* __restrict__ qkv, float* __restrict__ o)
{
    const int bh = blockIdx.x;
    const int b = bh >> 2;
    const int h = bh & 3;

    __shared__ short Qs[SP_ * 32];    // [i][c] bf16 (q*scale); rows 72..79 = 0
    __shared__ short Ks[SP_ * 32];    // [j][c] bf16; rows 72..79 = 0
    __shared__ short VT[32 * KP_];    // [c][j] bf16; j 72..95 = 0
    __shared__ short Pb[SP_ * KP_];   // [i][j] bf16 exp(s-mx); j 72..95 = 0

    const int tid = threadIdx.x;
    const int lane = tid & 63;
    const int wid = tid >> 6;         // 0..3
    const int g = lane >> 4;          // 0..3
    const int c16 = lane & 15;

    const float scale = 0.17677669529663687f;  // 1/sqrt(32)

    for (int idx = tid; idx < S_ * 8; idx += 256) {
        const int i = idx >> 3;
        const int c4 = (idx & 7) * 4;
        const size_t base = ((size_t)(b * S_ + i)) * 384 + h * 32 + c4;
        const float4 q = *reinterpret_cast<const float4*>(&qkv[base]);
        const float4 k = *reinterpret_cast<const float4*>(&qkv[base + 128]);
        const float4 v = *reinterpret_cast<const float4*>(&qkv[base + 256]);
        short4 qh, kh;
        qh.x = f2bf(q.x * scale); qh.y = f2bf(q.y * scale);
        qh.z = f2bf(q.z * scale); qh.w = f2bf(q.w * scale);
        kh.x = f2bf(k.x); kh.y = f2bf(k.y);
        kh.z = f2bf(k.z); kh.w = f2bf(k.w);
        *reinterpret_cast<short4*>(&Qs[i * 32 + c4]) = qh;
        *reinterpret_cast<short4*>(&Ks[i * 32 + c4]) = kh;
        VT[(c4 + 0) * KP_ + i] = f2bf(v.x);
        VT[(c4 + 1) * KP_ + i] = f2bf(v.y);
        VT[(c4 + 2) * KP_ + i] = f2bf(v.z);
        VT[(c4 + 3) * KP_ + i] = f2bf(v.w);
    }
    for (int idx = tid; idx < 8 * 32; idx += 256) {   // Q/K rows 72..79
        Qs[S_ * 32 + idx] = 0;
        Ks[S_ * 32 + idx] = 0;
    }
    for (int idx = tid; idx < 32 * 24; idx += 256) {  // VT j = 72..95
        VT[(idx / 24) * KP_ + 72 + idx % 24] = 0;
    }
    for (int idx = tid; idx < SP_ * 24; idx += 256) { // Pb j = 72..95
        Pb[(idx / 24) * KP_ + 72 + idx % 24] = 0;
    }
    __syncthreads();

    float invr[2][4];
#pragma unroll
    for (int mi = 0; mi < 2; ++mi) {
        const int m = wid + 4 * mi;
        if (m <= 4) {
            const int rowb = m * 16;
            const bf16x8 aF = *reinterpret_cast<const bf16x8*>(
                &Qs[(rowb + c16) * 32 + 8 * g]);
            f32x4 sc[5];
#pragma unroll
            for (int n = 0; n < 5; ++n) {
                const bf16x8 bF = *reinterpret_cast<const bf16x8*>(
                    &Ks[(n * 16 + c16) * 32 + 8 * g]);
                f32x4 z = {};
                sc[n] = __builtin_amdgcn_mfma_f32_16x16x32_bf16(aF, bF, z, 0, 0, 0);
            }
#pragma unroll
            for (int j = 0; j < 4; ++j) {
                float mx = -1e30f;
#pragma unroll
                for (int n = 0; n < 5; ++n) {
                    const int col = n * 16 + c16;
                    if (col < S_) mx = fmaxf(mx, sc[n][j]);
                }
                mx = fmaxf(mx, __shfl_xor(mx, 1));
                mx = fmaxf(mx, __shfl_xor(mx, 2));
                mx = fmaxf(mx, __shfl_xor(mx, 4));
                mx = fmaxf(mx, __shfl_xor(mx, 8));
                float den = 0.f;
                float p[5];
#pragma unroll
                for (int n = 0; n < 5; ++n) {
                    const int col = n * 16 + c16;
                    p[n] = (col < S_) ? __expf(sc[n][j] - mx) : 0.f;
                    den += p[n];
                }
                den += __shfl_xor(den, 1);
                den += __shfl_xor(den, 2);
                den += __shfl_xor(den, 4);
                den += __shfl_xor(den, 8);
                invr[mi][j] = 1.f / den;
                const int row = rowb + 4 * g + j;
#pragma unroll
                for (int n = 0; n < 5; ++n)
                    Pb[row * KP_ + n * 16 + c16] = f2bf(p[n]);
            }
        }
    }
    __syncthreads();

#pragma unroll
    for (int mi = 0; mi < 2; ++mi) {
        const int m = wid + 4 * mi;
        if (m <= 4) {
            const int rowb = m * 16;
            f32x4 accO[2] = {};
#pragma unroll
            for (int kk = 0; kk < 3; ++kk) {
                const bf16x8 aF = *reinterpret_cast<const bf16x8*>(
                    &Pb[(rowb + c16) * KP_ + kk * 32 + 8 * g]);
#pragma unroll
                for (int n2 = 0; n2 < 2; ++n2) {
                    const bf16x8 bF = *reinterpret_cast<const bf16x8*>(
                        &VT[(n2 * 16 + c16) * KP_ + kk * 32 + 8 * g]);
                    accO[n2] = __builtin_amdgcn_mfma_f32_16x16x32_bf16(
                        aF, bF, accO[n2], 0, 0, 0);
                }
            }
#pragma unroll
            for (int j = 0; j < 4; ++j) {
                const int row = rowb + 4 * g + j;
                if (row < S_) {
                    const float inv = invr[mi][j];
#pragma unroll
                    for (int n2 = 0; n2 < 2; ++n2) {
                        o[((size_t)(b * S_ + row)) * D_ + h * 32 + n2 * 16 + c16]
                            = accO[n2][j] * inv;
                    }
                }
            }
        }
    }
}

// ---------------------------------------------------------------------------
// Kernel 5: head MLP. One 64-thread block per (k, b).
// ---------------------------------------------------------------------------
__global__ __launch_bounds__(64) void head_kernel(
    const float* __restrict__ t, const float* __restrict__ h1_w,
    const float* __restrict__ h1_b, const float* __restrict__ h2_w,
    const float* __restrict__ h2_b, float* __restrict__ out)
{
    const int kb = blockIdx.x;
    const int k = kb / B_;
    const int b = kb - k * B_;
    const int o = threadIdx.x;  // 0..63

    const float* xr = &t[((size_t)(b * S_ + S_ - 1)) * D_];
    const float* wr = &h1_w[((size_t)k * 64 + o) * D_];
    float acc = h1_b[k * 64 + o];
#pragma unroll 8
    for (int d = 0; d < D_; ++d) acc = fmaf(xr[d], wr[d], acc);
    const float h1v = fmaxf(acc, 0.f);

#pragma unroll
    for (int p = 0; p < NS_; ++p) {
        float partial = h1v * h2_w[((size_t)k * NS_ + p) * 64 + o];
#pragma unroll
        for (int off = 32; off >= 1; off >>= 1) partial += __shfl_xor(partial, off);
        if (o == 0) out[((size_t)k * B_ + b) * NS_ + p] = partial + h2_b[k * NS_ + p];
    }
}

// ---------------------------------------------------------------------------
extern "C" void kernel_launch(void* const* d_in, const int* in_sizes, int n_in,
                              void* d_out, int out_size, void* d_ws, size_t ws_size,
                              hipStream_t stream) {
    const float* x        = (const float*)d_in[0];
    // d_in[1] = edge_index: graph is complete + self loops; structure hardcoded
    const float* gat_w    = (const float*)d_in[2];
    const float* att_src  = (const float*)d_in[3];
    const float* att_dst  = (const float*)d_in[4];
    const float* gat_bias = (const float*)d_in[5];
    const float* gat_ln_g = (const float*)d_in[6];
    const float* gat_ln_b = (const float*)d_in[7];
    const float* qkv_w    = (const float*)d_in[8];
    const float* qkv_b    = (const float*)d_in[9];
    const float* out_w    = (const float*)d_in[10];
    const float* out_b    = (const float*)d_in[11];
    const float* ln1_g    = (const float*)d_in[12];
    const float* ln1_b    = (const float*)d_in[13];
    const float* ff1_w    = (const float*)d_in[14];
    const float* ff1_b    = (const float*)d_in[15];
    const float* ff2_w    = (const float*)d_in[16];
    const float* ff2_b    = (const float*)d_in[17];
    const float* ln2_g    = (const float*)d_in[18];
    const float* ln2_b    = (const float*)d_in[19];
    const float* h1_w     = (const float*)d_in[20];
    const float* h1_b     = (const float*)d_in[21];
    const float* h2_w     = (const float*)d_in[22];
    const float* h2_b     = (const float*)d_in[23];
    float* out = (float*)d_out;

    // scratch layout (floats): t | qkv | fbuf(attn-out alias) | pe
    float* ws   = (float*)d_ws;
    float* t    = ws;
    float* qkv  = t + (size_t)G_ * D_;          // G*384
    float* fbuf = qkv + (size_t)G_ * 384;       // G*256 (attn out uses G*128 of it)
    float* pe   = fbuf + (size_t)G_ * FF_;      // S*128

    pe_kernel<<<S_, 128, 0, stream>>>(pe);
    gat_kernel<<<G_, 128, 0, stream>>>(x, gat_w, att_src, att_dst,
                                       gat_bias, gat_ln_g, gat_ln_b, pe, t);

    for (int l = 0; l < L_; ++l) {
        linear_mfma_kernel<<<dim3(G_ / 64, 384 / 64), 256, 0, stream>>>(
            t, qkv_w + (size_t)l * 384 * D_, qkv_b + (size_t)l * 384, qkv,
            D_, 384, 0);
        attn_mfma_kernel<<<B_ * H_, 256, 0, stream>>>(qkv, fbuf);
        // fused: t = LN(t + fbuf*out_w^T + out_b)
        linear_ln_kernel<<<G_ / 64, 256, 0, stream>>>(
            fbuf, out_w + (size_t)l * D_ * D_, out_b + (size_t)l * D_, t,
            ln1_g + l * D_, ln1_b + l * D_, D_);
        linear_mfma_kernel<<<dim3(G_ / 64, FF_ / 64), 256, 0, stream>>>(
            t, ff1_w + (size_t)l * FF_ * D_, ff1_b + (size_t)l * FF_, fbuf,
            D_, FF_, 1);
        // fused: t = LN(t + fbuf*ff2_w^T + ff2_b)
        linear_ln_kernel<<<G_ / 64, 256, 0, stream>>>(
            fbuf, ff2_w + (size_t)l * D_ * FF_, ff2_b + (size_t)l * D_, t,
            ln2_g + l * D_, ln2_b + l * D_, FF_);
    }

    head_kernel<<<K_ * B_, 64, 0, stream>>>(t, h1_w, h1_b, h2_w, h2_b, out);
}

// Round 11
// 470.152 us; speedup vs baseline: 1.1720x; 1.0496x over previous
//
#include <hip/hip_runtime.h>
#include <math.h>

// Problem constants
constexpr int B_ = 512, S_ = 72, N_ = 5, F_ = 10;
constexpr int H_ = 4, C_ = 32, D_ = 128;
constexpr int L_ = 3, FF_ = 256;
constexpr int K_ = 6, NS_ = 5;
constexpr int G_ = B_ * S_;           // 36864
constexpr float EPS_ = 1e-5f;
constexpr int SP_ = 80;               // S padded to 5*16 for MFMA fragments
constexpr int KP_ = 96;               // PV K-dim padded to 3*32

typedef short bf16x8 __attribute__((ext_vector_type(8)));
typedef float f32x4 __attribute__((ext_vector_type(4)));

__device__ __forceinline__ short f2bf(float f) {
    unsigned int u = __float_as_uint(f);
    u += 0x7FFFu + ((u >> 16) & 1u);      // round-to-nearest-even
    return (short)(u >> 16);
}

// ---------------------------------------------------------------------------
// Kernel 0a: positional-encoding table (S x D), once per launch.
// ---------------------------------------------------------------------------
__global__ __launch_bounds__(128) void pe_kernel(float* __restrict__ pe)
{
    const int s = blockIdx.x;           // 0..71
    const int d = threadIdx.x;          // 0..127
    const float expo = -(float)(d & ~1) * (9.210340371976184f / 128.f);
    const float ang = (float)s * expf(expo);
    pe[s * D_ + d] = (d & 1) ? cosf(ang) : sinf(ang);
}

// ---------------------------------------------------------------------------
// Kernel 0b: GAT attention-logit factorization tables, once per launch.
//   wsrc[f,h] = sum_c W[f, h*32+c] * att_src[h*32+c]   (a_src = x @ wsrc)
//   wdst[f,h] = sum_c W[f, h*32+c] * att_dst[h*32+c]
// gatc layout: [wsrc(40) | wdst(40)]. One block, serial 32-FMA dots (trivial).
// ---------------------------------------------------------------------------
__global__ __launch_bounds__(128) void gatc_kernel(
    const float* __restrict__ gat_w, const float* __restrict__ att_src,
    const float* __restrict__ att_dst, float* __restrict__ gatc)
{
    const int t = threadIdx.x;
    if (t < 40) {
        const int f = t >> 2, h = t & 3;
        float s = 0.f;
#pragma unroll
        for (int c = 0; c < 32; ++c)
            s = fmaf(gat_w[f * D_ + h * 32 + c], att_src[h * 32 + c], s);
        gatc[t] = s;
    } else if (t < 80) {
        const int f = (t - 40) >> 2, h = (t - 40) & 3;
        float s = 0.f;
#pragma unroll
        for (int c = 0; c < 32; ++c)
            s = fmaf(gat_w[f * D_ + h * 32 + c], att_dst[h * 32 + c], s);
        gatc[t] = s;
    }
}

// ---------------------------------------------------------------------------
// Kernel 1: fused GAT -> layernorm -> node-mean -> +pe.
// r10: attention logits via factorized 10-FMA dots (gatc tables) — removes
// the 50 ds_swizzle butterfly reductions + 2 barriers per thread that the
// r9 profile showed to be the bottleneck (VALUBusy 62%, trig removal ~no-op).
// ---------------------------------------------------------------------------
__global__ __launch_bounds__(128) void gat_kernel(
    const float* __restrict__ x,        // (G, N, F)
    const float* __restrict__ gat_w,    // (F, D)
    const float* __restrict__ gatc,     // [wsrc(40)|wdst(40)]
    const float* __restrict__ gat_bias, // (D)
    const float* __restrict__ ln_g,     // (D)
    const float* __restrict__ ln_b,     // (D)
    const float* __restrict__ pe,       // (S, D)
    float* __restrict__ t_out)          // (G, D)
{
    const int g = blockIdx.x;
    const int d = threadIdx.x;          // 0..127
    const int s = g % S_;
    const int head = d >> 5;

    __shared__ float xs[N_][F_];
    __shared__ float red[N_][2][2];     // [n][wave][sum, sumsq]

    if (d < N_ * F_) xs[d / F_][d % F_] = x[(size_t)g * N_ * F_ + d];
    __syncthreads();

    float wcol[F_], wsrcv[F_], wdstv[F_];
#pragma unroll
    for (int f = 0; f < F_; ++f) {
        wcol[f]  = gat_w[f * D_ + d];
        wsrcv[f] = gatc[f * 4 + head];
        wdstv[f] = gatc[40 + f * 4 + head];
    }

    // one xs read feeds h, a_src, a_dst
    float hn[N_], a_s[N_], a_d[N_];
#pragma unroll
    for (int n = 0; n < N_; ++n) {
        float acc = 0.f, ss = 0.f, dd = 0.f;
#pragma unroll
        for (int f = 0; f < F_; ++f) {
            const float xv = xs[n][f];
            acc = fmaf(xv, wcol[f], acc);
            ss  = fmaf(xv, wsrcv[f], ss);
            dd  = fmaf(xv, wdstv[f], dd);
        }
        hn[n] = acc; a_s[n] = ss; a_d[n] = dd;
    }

    float y[N_];
#pragma unroll
    for (int n = 0; n < N_; ++n) {
        const float ad = a_d[n];
        float e[N_];
        float mx = -1e30f;
#pragma unroll
        for (int m = 0; m < N_; ++m) {
            float v = a_s[m] + ad;
            v = v > 0.f ? v : 0.2f * v;       // leaky_relu(0.2)
            e[m] = v;
            mx = fmaxf(mx, v);
        }
        float den = 0.f;
#pragma unroll
        for (int m = 0; m < N_; ++m) { e[m] = __expf(e[m] - mx); den += e[m]; }
        const float inv = 1.f / den;
        float agg = 0.f;
#pragma unroll
        for (int m = 0; m < N_; ++m) agg = fmaf(e[m] * inv, hn[m], agg);
        y[n] = agg + gat_bias[d];
    }

    const int wave = d >> 6;
#pragma unroll
    for (int n = 0; n < N_; ++n) {
        float sm = y[n];
        float sq = y[n] * y[n];
#pragma unroll
        for (int off = 32; off >= 1; off >>= 1) {
            sm += __shfl_xor(sm, off);
            sq += __shfl_xor(sq, off);
        }
        if ((d & 63) == 0) { red[n][wave][0] = sm; red[n][wave][1] = sq; }
    }
    __syncthreads();

    const float gg = ln_g[d];
    const float bb = ln_b[d];
    float tacc = 0.f;
#pragma unroll
    for (int n = 0; n < N_; ++n) {
        const float sm = red[n][0][0] + red[n][1][0];
        const float sq = red[n][0][1] + red[n][1][1];
        const float mean = sm * (1.f / D_);
        const float var = sq * (1.f / D_) - mean * mean;
        const float rstd = rsqrtf(var + EPS_);
        tacc += (y[n] - mean) * rstd * gg + bb;
    }
    tacc *= (1.f / N_);

    t_out[(size_t)g * D_ + d] = tacc + pe[s * D_ + d];
}

// ---------------------------------------------------------------------------
// Kernel 2: bf16-MFMA linear (HW-validated r7): out = act(A*W^T + bias).
// ---------------------------------------------------------------------------
__global__ __launch_bounds__(256) void linear_mfma_kernel(
    const float* __restrict__ A, const float* __restrict__ W,
    const float* __restrict__ bias, float* __restrict__ out,
    int K, int Cout, int relu)
{
    __shared__ short As[64 * 64];   // [row][k], 8KB
    __shared__ short Ws[64 * 64];   // [col][k], 8KB

    const int tid = threadIdx.x;
    const int lane = tid & 63;
    const int wid = tid >> 6;       // 0..3
    const int wr = wid >> 1;        // wave row (0/1)
    const int wc = wid & 1;         // wave col (0/1)
    const int r0 = blockIdx.x * 64;
    const int c0 = blockIdx.y * 64;

    const int st_row = tid >> 3;    // 0..31 (+32 on second iter)
    const int st_slot = tid & 7;    // k-slot (8 bf16 = 16B)

    f32x4 acc[2][2] = {};

    for (int kk = 0; kk < K; kk += 64) {
        if (kk) __syncthreads();
#pragma unroll
        for (int it = 0; it < 2; ++it) {
            const int row = st_row + it * 32;
            const int gk = kk + st_slot * 8;
            const int pslot = st_slot ^ (row & 7);
            {
                const float* src = &A[(size_t)(r0 + row) * K + gk];
                const float4 a0 = *reinterpret_cast<const float4*>(src);
                const float4 a1 = *reinterpret_cast<const float4*>(src + 4);
                bf16x8 h;
                h[0] = f2bf(a0.x); h[1] = f2bf(a0.y);
                h[2] = f2bf(a0.z); h[3] = f2bf(a0.w);
                h[4] = f2bf(a1.x); h[5] = f2bf(a1.y);
                h[6] = f2bf(a1.z); h[7] = f2bf(a1.w);
                *reinterpret_cast<bf16x8*>(&As[row * 64 + pslot * 8]) = h;
            }
            {
                const float* src = &W[(size_t)(c0 + row) * K + gk];
                const float4 w0 = *reinterpret_cast<const float4*>(src);
                const float4 w1 = *reinterpret_cast<const float4*>(src + 4);
                bf16x8 h;
                h[0] = f2bf(w0.x); h[1] = f2bf(w0.y);
                h[2] = f2bf(w0.z); h[3] = f2bf(w0.w);
                h[4] = f2bf(w1.x); h[5] = f2bf(w1.y);
                h[6] = f2bf(w1.z); h[7] = f2bf(w1.w);
                *reinterpret_cast<bf16x8*>(&Ws[row * 64 + pslot * 8]) = h;
            }
        }
        __syncthreads();

#pragma unroll
        for (int j = 0; j < 2; ++j) {
            bf16x8 aF[2], bF[2];
#pragma unroll
            for (int m = 0; m < 2; ++m) {
                const int row = wr * 32 + m * 16 + (lane & 15);
                const int slot = j * 4 + (lane >> 4);
                const int pslot = slot ^ (row & 7);
                aF[m] = *reinterpret_cast<const bf16x8*>(&As[row * 64 + pslot * 8]);
            }
#pragma unroll
            for (int n = 0; n < 2; ++n) {
                const int col = wc * 32 + n * 16 + (lane & 15);
                const int slot = j * 4 + (lane >> 4);
                const int pslot = slot ^ (col & 7);
                bF[n] = *reinterpret_cast<const bf16x8*>(&Ws[col * 64 + pslot * 8]);
            }
#pragma unroll
            for (int m = 0; m < 2; ++m)
#pragma unroll
                for (int n = 0; n < 2; ++n)
                    acc[m][n] = __builtin_amdgcn_mfma_f32_16x16x32_bf16(
                        aF[m], bF[n], acc[m][n], 0, 0, 0);
        }
    }

#pragma unroll
    for (int m = 0; m < 2; ++m) {
#pragma unroll
        for (int n = 0; n < 2; ++n) {
            const int col = c0 + wc * 32 + n * 16 + (lane & 15);
            const float bv = bias[col];
#pragma unroll
            for (int j = 0; j < 4; ++j) {
                const int row = r0 + wr * 32 + m * 16 + (lane >> 4) * 4 + j;
                float v = acc[m][n][j] + bv;
                if (relu) v = fmaxf(v, 0.f);
                out[(size_t)row * Cout + col] = v;
            }
        }
    }
}

// ---------------------------------------------------------------------------
// Kernel 2b: bf16-MFMA linear (Cout=128) fused residual-add + LayerNorm
// (HW-validated r9): t[r,:] = LN(t[r,:] + A[r]*W^T + bias) in place.
// ---------------------------------------------------------------------------
__global__ __launch_bounds__(256) void linear_ln_kernel(
    const float* __restrict__ A, const float* __restrict__ W,
    const float* __restrict__ bias, float* __restrict__ t,
    const float* __restrict__ lng, const float* __restrict__ lnb,
    int K)
{
    __shared__ short As[64 * 64];    // 8KB
    __shared__ short Ws2[128 * 64];  // 16KB
    __shared__ float red[64][2][2];  // [row][wc][sum,sumsq], 1KB

    const int tid = threadIdx.x;
    const int lane = tid & 63;
    const int wid = tid >> 6;       // 0..3
    const int wr = wid >> 1;        // 0/1: rows 32*wr..
    const int wc = wid & 1;         // 0/1: cols 64*wc..
    const int c16 = lane & 15;
    const int grp = lane >> 4;      // 0..3
    const int r0 = blockIdx.x * 64;

    const int st_row = tid >> 3;    // 0..31
    const int st_slot = tid & 7;

    f32x4 acc[2][4] = {};

    for (int kk = 0; kk < K; kk += 64) {
        if (kk) __syncthreads();
#pragma unroll
        for (int it = 0; it < 2; ++it) {
            const int row = st_row + it * 32;
            const int gk = kk + st_slot * 8;
            const int pslot = st_slot ^ (row & 7);
            const float* src = &A[(size_t)(r0 + row) * K + gk];
            const float4 a0 = *reinterpret_cast<const float4*>(src);
            const float4 a1 = *reinterpret_cast<const float4*>(src + 4);
            bf16x8 h;
            h[0] = f2bf(a0.x); h[1] = f2bf(a0.y);
            h[2] = f2bf(a0.z); h[3] = f2bf(a0.w);
            h[4] = f2bf(a1.x); h[5] = f2bf(a1.y);
            h[6] = f2bf(a1.z); h[7] = f2bf(a1.w);
            *reinterpret_cast<bf16x8*>(&As[row * 64 + pslot * 8]) = h;
        }
#pragma unroll
        for (int it = 0; it < 4; ++it) {
            const int row = st_row + it * 32;
            const int gk = kk + st_slot * 8;
            const int pslot = st_slot ^ (row & 7);
            const float* src = &W[(size_t)row * K + gk];
            const float4 w0 = *reinterpret_cast<const float4*>(src);
            const float4 w1 = *reinterpret_cast<const float4*>(src + 4);
            bf16x8 h;
            h[0] = f2bf(w0.x); h[1] = f2bf(w0.y);
            h[2] = f2bf(w0.z); h[3] = f2bf(w0.w);
            h[4] = f2bf(w1.x); h[5] = f2bf(w1.y);
            h[6] = f2bf(w1.z); h[7] = f2bf(w1.w);
            *reinterpret_cast<bf16x8*>(&Ws2[row * 64 + pslot * 8]) = h;
        }
        __syncthreads();

#pragma unroll
        for (int j = 0; j < 2; ++j) {
            bf16x8 aF[2], bF[4];
#pragma unroll
            for (int m = 0; m < 2; ++m) {
                const int row = wr * 32 + m * 16 + c16;
                const int slot = j * 4 + grp;
                const int pslot = slot ^ (row & 7);
                aF[m] = *reinterpret_cast<const bf16x8*>(&As[row * 64 + pslot * 8]);
            }
#pragma unroll
            for (int n = 0; n < 4; ++n) {
                const int col = wc * 64 + n * 16 + c16;
                const int slot = j * 4 + grp;
                const int pslot = slot ^ (col & 7);
                bF[n] = *reinterpret_cast<const bf16x8*>(&Ws2[col * 64 + pslot * 8]);
            }
#pragma unroll
            for (int m = 0; m < 2; ++m)
#pragma unroll
                for (int n = 0; n < 4; ++n)
                    acc[m][n] = __builtin_amdgcn_mfma_f32_16x16x32_bf16(
                        aF[m], bF[n], acc[m][n], 0, 0, 0);
        }
    }

#pragma unroll
    for (int m = 0; m < 2; ++m) {
#pragma unroll
        for (int j = 0; j < 4; ++j) {
            const int row = wr * 32 + m * 16 + 4 * grp + j;
            float sm = 0.f, sq = 0.f;
#pragma unroll
            for (int n = 0; n < 4; ++n) {
                const int col = wc * 64 + n * 16 + c16;
                float v = acc[m][n][j] + bias[col]
                        + t[(size_t)(r0 + row) * D_ + col];
                acc[m][n][j] = v;
                sm += v;
                sq += v * v;
            }
#pragma unroll
            for (int off = 8; off >= 1; off >>= 1) {
                sm += __shfl_xor(sm, off);
                sq += __shfl_xor(sq, off);
            }
            if (c16 == 0) { red[row][wc][0] = sm; red[row][wc][1] = sq; }
        }
    }
    __syncthreads();

#pragma unroll
    for (int m = 0; m < 2; ++m) {
#pragma unroll
        for (int j = 0; j < 4; ++j) {
            const int row = wr * 32 + m * 16 + 4 * grp + j;
            const float sm = red[row][0][0] + red[row][1][0];
            const float sq = red[row][0][1] + red[row][1][1];
            const float mean = sm * (1.f / D_);
            const float var = sq * (1.f / D_) - mean * mean;
            const float rstd = rsqrtf(var + EPS_);
#pragma unroll
            for (int n = 0; n < 4; ++n) {
                const int col = wc * 64 + n * 16 + c16;
                t[(size_t)(r0 + row) * D_ + col] =
                    (acc[m][n][j] - mean) * rstd * lng[col] + lnb[col];
            }
        }
    }
}

// ---------------------------------------------------------------------------
// Kernel 3: bf16-MFMA attention (HW-validated r7).
// ---------------------------------------------------------------------------
__global__ __launch_bounds__(256) void attn_mfma_kernel(
    const float* __restrict__ qkv, float* __restrict__ o)
{
    const int bh = blockIdx.x;
    const int b = bh >> 2;
    const int h = bh & 3;

    __shared__ short Qs[SP_ * 32];    // [i][c] bf16 (q*scale); rows 72..79 = 0
    __shared__ short Ks[SP_ * 32];    // [j][c] bf16; rows 72..79 = 0
    __shared__ short VT[32 * KP_];    // [c][j] bf16; j 72..95 = 0
    __shared__ short Pb[SP_ * KP_];   // [i][j] bf16 exp(s-mx); j 72..95 = 0

    const int tid = threadIdx.x;
    const int lane = tid & 63;
    const int wid = tid >> 6;         // 0..3
    const int g = lane >> 4;          // 0..3
    const int c16 = lane & 15;

    const float scale = 0.17677669529663687f;  // 1/sqrt(32)

    for (int idx = tid; idx < S_ * 8; idx += 256) {
        const int i = idx >> 3;
        const int c4 = (idx & 7) * 4;
        const size_t base = ((size_t)(b * S_ + i)) * 384 + h * 32 + c4;
        const float4 q = *reinterpret_cast<const float4*>(&qkv[base]);
        const float4 k = *reinterpret_cast<const float4*>(&qkv[base + 128]);
        const float4 v = *reinterpret_cast<const float4*>(&qkv[base + 256]);
        short4 qh, kh;
        qh.x = f2bf(q.x * scale); qh.y = f2bf(q.y * scale);
        qh.z = f2bf(q.z * scale); qh.w = f2bf(q.w * scale);
        kh.x = f2bf(k.x); kh.y = f2bf(k.y);
        kh.z = f2bf(k.z); kh.w = f2bf(k.w);
        *reinterpret_cast<short4*>(&Qs[i * 32 + c4]) = qh;
        *reinterpret_cast<short4*>(&Ks[i * 32 + c4]) = kh;
        VT[(c4 + 0) * KP_ + i] = f2bf(v.x);
        VT[(c4 + 1) * KP_ + i] = f2bf(v.y);
        VT[(c4 + 2) * KP_ + i] = f2bf(v.z);
        VT[(c4 + 3) * KP_ + i] = f2bf(v.w);
    }
    for (int idx = tid; idx < 8 * 32; idx += 256) {   // Q/K rows 72..79
        Qs[S_ * 32 + idx] = 0;
        Ks[S_ * 32 + idx] = 0;
    }
    for (int idx = tid; idx < 32 * 24; idx += 256) {  // VT j = 72..95
        VT[(idx / 24) * KP_ + 72 + idx % 24] = 0;
    }
    for (int idx = tid; idx < SP_ * 24; idx += 256) { // Pb j = 72..95
        Pb[(idx / 24) * KP_ + 72 + idx % 24] = 0;
    }
    __syncthreads();

    float invr[2][4];
#pragma unroll
    for (int mi = 0; mi < 2; ++mi) {
        const int m = wid + 4 * mi;
        if (m <= 4) {
            const int rowb = m * 16;
            const bf16x8 aF = *reinterpret_cast<const bf16x8*>(
                &Qs[(rowb + c16) * 32 + 8 * g]);
            f32x4 sc[5];
#pragma unroll
            for (int n = 0; n < 5; ++n) {
                const bf16x8 bF = *reinterpret_cast<const bf16x8*>(
                    &Ks[(n * 16 + c16) * 32 + 8 * g]);
                f32x4 z = {};
                sc[n] = __builtin_amdgcn_mfma_f32_16x16x32_bf16(aF, bF, z, 0, 0, 0);
            }
#pragma unroll
            for (int j = 0; j < 4; ++j) {
                float mx = -1e30f;
#pragma unroll
                for (int n = 0; n < 5; ++n) {
                    const int col = n * 16 + c16;
                    if (col < S_) mx = fmaxf(mx, sc[n][j]);
                }
                mx = fmaxf(mx, __shfl_xor(mx, 1));
                mx = fmaxf(mx, __shfl_xor(mx, 2));
                mx = fmaxf(mx, __shfl_xor(mx, 4));
                mx = fmaxf(mx, __shfl_xor(mx, 8));
                float den = 0.f;
                float p[5];
#pragma unroll
                for (int n = 0; n < 5; ++n) {
                    const int col = n * 16 + c16;
                    p[n] = (col < S_) ? __expf(sc[n][j] - mx) : 0.f;
                    den += p[n];
                }
                den += __shfl_xor(den, 1);
                den += __shfl_xor(den, 2);
                den += __shfl_xor(den, 4);
                den += __shfl_xor(den, 8);
                invr[mi][j] = 1.f / den;
                const int row = rowb + 4 * g + j;
#pragma unroll
                for (int n = 0; n < 5; ++n)
                    Pb[row * KP_ + n * 16 + c16] = f2bf(p[n]);
            }
        }
    }
    __syncthreads();

#pragma unroll
    for (int mi = 0; mi < 2; ++mi) {
        const int m = wid + 4 * mi;
        if (m <= 4) {
            const int rowb = m * 16;
            f32x4 accO[2] = {};
#pragma unroll
            for (int kk = 0; kk < 3; ++kk) {
                const bf16x8 aF = *reinterpret_cast<const bf16x8*>(
                    &Pb[(rowb + c16) * KP_ + kk * 32 + 8 * g]);
#pragma unroll
                for (int n2 = 0; n2 < 2; ++n2) {
                    const bf16x8 bF = *reinterpret_cast<const bf16x8*>(
                        &VT[(n2 * 16 + c16) * KP_ + kk * 32 + 8 * g]);
                    accO[n2] = __builtin_amdgcn_mfma_f32_16x16x32_bf16(
                        aF, bF, accO[n2], 0, 0, 0);
                }
            }
#pragma unroll
            for (int j = 0; j < 4; ++j) {
                const int row = rowb + 4 * g + j;
                if (row < S_) {
                    const float inv = invr[mi][j];
#pragma unroll
                    for (int n2 = 0; n2 < 2; ++n2) {
                        o[((size_t)(b * S_ + row)) * D_ + h * 32 + n2 * 16 + c16]
                            = accO[n2][j] * inv;
                    }
                }
            }
        }
    }
}

// ---------------------------------------------------------------------------
// Kernel 5: head MLP. One 64-thread block per (k, b).
// ---------------------------------------------------------------------------
__global__ __launch_bounds__(64) void head_kernel(
    const float* __restrict__ t, const float* __restrict__ h1_w,
    const float* __restrict__ h1_b, const float* __restrict__ h2_w,
    const float* __restrict__ h2_b, float* __restrict__ out)
{
    const int kb = blockIdx.x;
    const int k = kb / B_;
    const int b = kb - k * B_;
    const int o = threadIdx.x;  // 0..63

    const float* xr = &t[((size_t)(b * S_ + S_ - 1)) * D_];
    const float* wr = &h1_w[((size_t)k * 64 + o) * D_];
    float acc = h1_b[k * 64 + o];
#pragma unroll 8
    for (int d = 0; d < D_; ++d) acc = fmaf(xr[d], wr[d], acc);
    const float h1v = fmaxf(acc, 0.f);

#pragma unroll
    for (int p = 0; p < NS_; ++p) {
        float partial = h1v * h2_w[((size_t)k * NS_ + p) * 64 + o];
#pragma unroll
        for (int off = 32; off >= 1; off >>= 1) partial += __shfl_xor(partial, off);
        if (o == 0) out[((size_t)k * B_ + b) * NS_ + p] = partial + h2_b[k * NS_ + p];
    }
}

// ---------------------------------------------------------------------------
extern "C" void kernel_launch(void* const* d_in, const int* in_sizes, int n_in,
                              void* d_out, int out_size, void* d_ws, size_t ws_size,
                              hipStream_t stream) {
    const float* x        = (const float*)d_in[0];
    // d_in[1] = edge_index: graph is complete + self loops; structure hardcoded
    const float* gat_w    = (const float*)d_in[2];
    const float* att_src  = (const float*)d_in[3];
    const float* att_dst  = (const float*)d_in[4];
    const float* gat_bias = (const float*)d_in[5];
    const float* gat_ln_g = (const float*)d_in[6];
    const float* gat_ln_b = (const float*)d_in[7];
    const float* qkv_w    = (const float*)d_in[8];
    const float* qkv_b    = (const float*)d_in[9];
    const float* out_w    = (const float*)d_in[10];
    const float* out_b    = (const float*)d_in[11];
    const float* ln1_g    = (const float*)d_in[12];
    const float* ln1_b    = (const float*)d_in[13];
    const float* ff1_w    = (const float*)d_in[14];
    const float* ff1_b    = (const float*)d_in[15];
    const float* ff2_w    = (const float*)d_in[16];
    const float* ff2_b    = (const float*)d_in[17];
    const float* ln2_g    = (const float*)d_in[18];
    const float* ln2_b    = (const float*)d_in[19];
    const float* h1_w     = (const float*)d_in[20];
    const float* h1_b     = (const float*)d_in[21];
    const float* h2_w     = (const float*)d_in[22];
    const float* h2_b     = (const float*)d_in[23];
    float* out = (float*)d_out;

    // scratch layout (floats): t | qkv | fbuf | pe | gatc
    float* ws   = (float*)d_ws;
    float* t    = ws;
    float* qkv  = t + (size_t)G_ * D_;          // G*384
    float* fbuf = qkv + (size_t)G_ * 384;       // G*256 (attn out uses G*128 of it)
    float* pe   = fbuf + (size_t)G_ * FF_;      // S*128
    float* gatc = pe + (size_t)S_ * D_;         // 80

    pe_kernel<<<S_, 128, 0, stream>>>(pe);
    gatc_kernel<<<1, 128, 0, stream>>>(gat_w, att_src, att_dst, gatc);
    gat_kernel<<<G_, 128, 0, stream>>>(x, gat_w, gatc,
                                       gat_bias, gat_ln_g, gat_ln_b, pe, t);

    for (int l = 0; l < L_; ++l) {
        linear_mfma_kernel<<<dim3(G_ / 64, 384 / 64), 256, 0, stream>>>(
            t, qkv_w + (size_t)l * 384 * D_, qkv_b + (size_t)l * 384, qkv,
            D_, 384, 0);
        attn_mfma_kernel<<<B_ * H_, 256, 0, stream>>>(qkv, fbuf);
        // fused: t = LN(t + fbuf*out_w^T + out_b)
        linear_ln_kernel<<<G_ / 64, 256, 0, stream>>>(
            fbuf, out_w + (size_t)l * D_ * D_, out_b + (size_t)l * D_, t,
            ln1_g + l * D_, ln1_b + l * D_, D_);
        linear_mfma_kernel<<<dim3(G_ / 64, FF_ / 64), 256, 0, stream>>>(
            t, ff1_w + (size_t)l * FF_ * D_, ff1_b + (size_t)l * FF_, fbuf,
            D_, FF_, 1);
        // fused: t = LN(t + fbuf*ff2_w^T + ff2_b)
        linear_ln_kernel<<<G_ / 64, 256, 0, stream>>>(
            fbuf, ff2_w + (size_t)l * D_ * FF_, ff2_b + (size_t)l * D_, t,
            ln2_g + l * D_, ln2_b + l * D_, FF_);
    }

    head_kernel<<<K_ * B_, 64, 0, stream>>>(t, h1_w, h1_b, h2_w, h2_b, out);
}

// Round 13
// 418.556 us; speedup vs baseline: 1.3164x; 1.1233x over previous
//
#include <hip/hip_runtime.h>
#include <math.h>

// Problem constants
constexpr int B_ = 512, S_ = 72, N_ = 5, F_ = 10;
constexpr int H_ = 4, C_ = 32, D_ = 128;
constexpr int L_ = 3, FF_ = 256;
constexpr int K_ = 6, NS_ = 5;
constexpr int G_ = B_ * S_;           // 36864
constexpr float EPS_ = 1e-5f;
constexpr int SP_ = 80;               // S padded to 5*16 for MFMA fragments
constexpr int KP_ = 96;               // PV K-dim padded to 3*32

// bf16 weight arena offsets (shorts)
constexpr int WQKV_ = 0;                       // 3 * 384*128 = 147456
constexpr int WOUT_ = 147456;                  // 3 * 128*128 = 49152
constexpr int WFF1_ = 196608;                  // 3 * 256*128 = 98304
constexpr int WFF2_ = 294912;                  // 3 * 128*256 = 98304
constexpr int WTOT_ = 393216;

typedef short bf16x8 __attribute__((ext_vector_type(8)));
typedef float f32x4 __attribute__((ext_vector_type(4)));

__device__ __forceinline__ short f2bf(float f) {
    unsigned int u = __float_as_uint(f);
    u += 0x7FFFu + ((u >> 16) & 1u);      // round-to-nearest-even
    return (short)(u >> 16);
}

// ---------------------------------------------------------------------------
// Kernel 0a: positional-encoding table (S x D), once per launch.
// ---------------------------------------------------------------------------
__global__ __launch_bounds__(128) void pe_kernel(float* __restrict__ pe)
{
    const int s = blockIdx.x;           // 0..71
    const int d = threadIdx.x;          // 0..127
    const float expo = -(float)(d & ~1) * (9.210340371976184f / 128.f);
    const float ang = (float)s * expf(expo);
    pe[s * D_ + d] = (d & 1) ? cosf(ang) : sinf(ang);
}

// ---------------------------------------------------------------------------
// Kernel 0b: GAT attention-logit factorization tables (r10, HW-validated).
// ---------------------------------------------------------------------------
__global__ __launch_bounds__(128) void gatc_kernel(
    const float* __restrict__ gat_w, const float* __restrict__ att_src,
    const float* __restrict__ att_dst, float* __restrict__ gatc)
{
    const int t = threadIdx.x;
    if (t < 40) {
        const int f = t >> 2, h = t & 3;
        float s = 0.f;
#pragma unroll
        for (int c = 0; c < 32; ++c)
            s = fmaf(gat_w[f * D_ + h * 32 + c], att_src[h * 32 + c], s);
        gatc[t] = s;
    } else if (t < 80) {
        const int f = (t - 40) >> 2, h = (t - 40) & 3;
        float s = 0.f;
#pragma unroll
        for (int c = 0; c < 32; ++c)
            s = fmaf(gat_w[f * D_ + h * 32 + c], att_dst[h * 32 + c], s);
        gatc[t] = s;
    }
}

// ---------------------------------------------------------------------------
// Kernel 0c: convert ALL transformer weights fp32->bf16 ONCE per launch.
// r12: each weight was being re-converted by every one of the 576 blocks
// reading it (48 f2bf/thread/K-tile); now converted once (786 KB arena).
// Grid 384x256, 4 elements/thread = exactly WTOT_.
// ---------------------------------------------------------------------------
__global__ __launch_bounds__(256) void wcvt_kernel(
    const float* __restrict__ qw, const float* __restrict__ ow,
    const float* __restrict__ f1, const float* __restrict__ f2,
    short* __restrict__ wb)
{
    const int i4 = (blockIdx.x * 256 + threadIdx.x) * 4;
    const float* src; int off;
    if (i4 < WOUT_)      { src = qw; off = i4; }
    else if (i4 < WFF1_) { src = ow; off = i4 - WOUT_; }
    else if (i4 < WFF2_) { src = f1; off = i4 - WFF1_; }
    else                 { src = f2; off = i4 - WFF2_; }
    const float4 v = *reinterpret_cast<const float4*>(&src[off]);
    short4 h;
    h.x = f2bf(v.x); h.y = f2bf(v.y); h.z = f2bf(v.z); h.w = f2bf(v.w);
    *reinterpret_cast<short4*>(&wb[i4]) = h;
}

// ---------------------------------------------------------------------------
// Kernel 1: fused GAT -> layernorm -> node-mean -> +pe (r10 structure).
// r12: additionally emits bf16 copy tb for the qkv GEMM's A-operand.
// ---------------------------------------------------------------------------
__global__ __launch_bounds__(128) void gat_kernel(
    const float* __restrict__ x,        // (G, N, F)
    const float* __restrict__ gat_w,    // (F, D)
    const float* __restrict__ gatc,     // [wsrc(40)|wdst(40)]
    const float* __restrict__ gat_bias, // (D)
    const float* __restrict__ ln_g,     // (D)
    const float* __restrict__ ln_b,     // (D)
    const float* __restrict__ pe,       // (S, D)
    float* __restrict__ t_out,          // (G, D) fp32
    short* __restrict__ tb_out)         // (G, D) bf16
{
    const int g = blockIdx.x;
    const int d = threadIdx.x;          // 0..127
    const int s = g % S_;
    const int head = d >> 5;

    __shared__ float xs[N_][F_];
    __shared__ float red[N_][2][2];     // [n][wave][sum, sumsq]

    if (d < N_ * F_) xs[d / F_][d % F_] = x[(size_t)g * N_ * F_ + d];
    __syncthreads();

    float wcol[F_], wsrcv[F_], wdstv[F_];
#pragma unroll
    for (int f = 0; f < F_; ++f) {
        wcol[f]  = gat_w[f * D_ + d];
        wsrcv[f] = gatc[f * 4 + head];
        wdstv[f] = gatc[40 + f * 4 + head];
    }

    float hn[N_], a_s[N_], a_d[N_];
#pragma unroll
    for (int n = 0; n < N_; ++n) {
        float acc = 0.f, ss = 0.f, dd = 0.f;
#pragma unroll
        for (int f = 0; f < F_; ++f) {
            const float xv = xs[n][f];
            acc = fmaf(xv, wcol[f], acc);
            ss  = fmaf(xv, wsrcv[f], ss);
            dd  = fmaf(xv, wdstv[f], dd);
        }
        hn[n] = acc; a_s[n] = ss; a_d[n] = dd;
    }

    float y[N_];
#pragma unroll
    for (int n = 0; n < N_; ++n) {
        const float ad = a_d[n];
        float e[N_];
        float mx = -1e30f;
#pragma unroll
        for (int m = 0; m < N_; ++m) {
            float v = a_s[m] + ad;
            v = v > 0.f ? v : 0.2f * v;       // leaky_relu(0.2)
            e[m] = v;
            mx = fmaxf(mx, v);
        }
        float den = 0.f;
#pragma unroll
        for (int m = 0; m < N_; ++m) { e[m] = __expf(e[m] - mx); den += e[m]; }
        const float inv = 1.f / den;
        float agg = 0.f;
#pragma unroll
        for (int m = 0; m < N_; ++m) agg = fmaf(e[m] * inv, hn[m], agg);
        y[n] = agg + gat_bias[d];
    }

    const int wave = d >> 6;
#pragma unroll
    for (int n = 0; n < N_; ++n) {
        float sm = y[n];
        float sq = y[n] * y[n];
#pragma unroll
        for (int off = 32; off >= 1; off >>= 1) {
            sm += __shfl_xor(sm, off);
            sq += __shfl_xor(sq, off);
        }
        if ((d & 63) == 0) { red[n][wave][0] = sm; red[n][wave][1] = sq; }
    }
    __syncthreads();

    const float gg = ln_g[d];
    const float bb = ln_b[d];
    float tacc = 0.f;
#pragma unroll
    for (int n = 0; n < N_; ++n) {
        const float sm = red[n][0][0] + red[n][1][0];
        const float sq = red[n][0][1] + red[n][1][1];
        const float mean = sm * (1.f / D_);
        const float var = sq * (1.f / D_) - mean * mean;
        const float rstd = rsqrtf(var + EPS_);
        tacc += (y[n] - mean) * rstd * gg + bb;
    }
    tacc *= (1.f / N_);

    const float val = tacc + pe[s * D_ + d];
    t_out[(size_t)g * D_ + d] = val;
    tb_out[(size_t)g * D_ + d] = f2bf(val);
}

// ---------------------------------------------------------------------------
// Kernel 2: bf16-MFMA linear (r7 structure): out_bf16 = act(A*W^T + bias).
// r12: A, W already bf16 (16B load -> ds_write, no conversion); out bf16.
// ---------------------------------------------------------------------------
__global__ __launch_bounds__(256) void linear_mfma_kernel(
    const short* __restrict__ A, const short* __restrict__ W,
    const float* __restrict__ bias, short* __restrict__ out,
    int K, int Cout, int relu)
{
    __shared__ short As[64 * 64];   // [row][k], 8KB
    __shared__ short Ws[64 * 64];   // [col][k], 8KB

    const int tid = threadIdx.x;
    const int lane = tid & 63;
    const int wid = tid >> 6;       // 0..3
    const int wr = wid >> 1;        // wave row (0/1)
    const int wc = wid & 1;         // wave col (0/1)
    const int r0 = blockIdx.x * 64;
    const int c0 = blockIdx.y * 64;

    const int st_row = tid >> 3;    // 0..31 (+32 on second iter)
    const int st_slot = tid & 7;    // k-slot (8 bf16 = 16B)

    f32x4 acc[2][2] = {};

    for (int kk = 0; kk < K; kk += 64) {
        if (kk) __syncthreads();
#pragma unroll
        for (int it = 0; it < 2; ++it) {
            const int row = st_row + it * 32;
            const int gk = kk + st_slot * 8;
            const int pslot = st_slot ^ (row & 7);
            *reinterpret_cast<bf16x8*>(&As[row * 64 + pslot * 8]) =
                *reinterpret_cast<const bf16x8*>(&A[(size_t)(r0 + row) * K + gk]);
            *reinterpret_cast<bf16x8*>(&Ws[row * 64 + pslot * 8]) =
                *reinterpret_cast<const bf16x8*>(&W[(size_t)(c0 + row) * K + gk]);
        }
        __syncthreads();

#pragma unroll
        for (int j = 0; j < 2; ++j) {
            bf16x8 aF[2], bF[2];
#pragma unroll
            for (int m = 0; m < 2; ++m) {
                const int row = wr * 32 + m * 16 + (lane & 15);
                const int slot = j * 4 + (lane >> 4);
                const int pslot = slot ^ (row & 7);
                aF[m] = *reinterpret_cast<const bf16x8*>(&As[row * 64 + pslot * 8]);
            }
#pragma unroll
            for (int n = 0; n < 2; ++n) {
                const int col = wc * 32 + n * 16 + (lane & 15);
                const int slot = j * 4 + (lane >> 4);
                const int pslot = slot ^ (col & 7);
                bF[n] = *reinterpret_cast<const bf16x8*>(&Ws[col * 64 + pslot * 8]);
            }
#pragma unroll
            for (int m = 0; m < 2; ++m)
#pragma unroll
                for (int n = 0; n < 2; ++n)
                    acc[m][n] = __builtin_amdgcn_mfma_f32_16x16x32_bf16(
                        aF[m], bF[n], acc[m][n], 0, 0, 0);
        }
    }

#pragma unroll
    for (int m = 0; m < 2; ++m) {
#pragma unroll
        for (int n = 0; n < 2; ++n) {
            const int col = c0 + wc * 32 + n * 16 + (lane & 15);
            const float bv = bias[col];
#pragma unroll
            for (int j = 0; j < 4; ++j) {
                const int row = r0 + wr * 32 + m * 16 + (lane >> 4) * 4 + j;
                float v = acc[m][n][j] + bv;
                if (relu) v = fmaxf(v, 0.f);
                out[(size_t)row * Cout + col] = f2bf(v);
            }
        }
    }
}

// ---------------------------------------------------------------------------
// Kernel 2b: bf16-MFMA linear (Cout=128) fused residual-add + LayerNorm
// (r9 structure): t = LN(t + A*W^T + bias) in place; also emits bf16 tb.
// r12: A, W bf16 inputs.
// ---------------------------------------------------------------------------
__global__ __launch_bounds__(256) void linear_ln_kernel(
    const short* __restrict__ A, const short* __restrict__ W,
    const float* __restrict__ bias, float* __restrict__ t,
    short* __restrict__ tb,
    const float* __restrict__ lng, const float* __restrict__ lnb,
    int K)
{
    __shared__ short As[64 * 64];    // 8KB
    __shared__ short Ws2[128 * 64];  // 16KB
    __shared__ float red[64][2][2];  // [row][wc][sum,sumsq], 1KB

    const int tid = threadIdx.x;
    const int lane = tid & 63;
    const int wid = tid >> 6;       // 0..3
    const int wr = wid >> 1;        // 0/1: rows 32*wr..
    const int wc = wid & 1;         // 0/1: cols 64*wc..
    const int c16 = lane & 15;
    const int grp = lane >> 4;      // 0..3
    const int r0 = blockIdx.x * 64;

    const int st_row = tid >> 3;    // 0..31
    const int st_slot = tid & 7;

    f32x4 acc[2][4] = {};

    for (int kk = 0; kk < K; kk += 64) {
        if (kk) __syncthreads();
#pragma unroll
        for (int it = 0; it < 2; ++it) {
            const int row = st_row + it * 32;
            const int gk = kk + st_slot * 8;
            const int pslot = st_slot ^ (row & 7);
            *reinterpret_cast<bf16x8*>(&As[row * 64 + pslot * 8]) =
                *reinterpret_cast<const bf16x8*>(&A[(size_t)(r0 + row) * K + gk]);
        }
#pragma unroll
        for (int it = 0; it < 4; ++it) {
            const int row = st_row + it * 32;
            const int gk = kk + st_slot * 8;
            const int pslot = st_slot ^ (row & 7);
            *reinterpret_cast<bf16x8*>(&Ws2[row * 64 + pslot * 8]) =
                *reinterpret_cast<const bf16x8*>(&W[(size_t)row * K + gk]);
        }
        __syncthreads();

#pragma unroll
        for (int j = 0; j < 2; ++j) {
            bf16x8 aF[2], bF[4];
#pragma unroll
            for (int m = 0; m < 2; ++m) {
                const int row = wr * 32 + m * 16 + c16;
                const int slot = j * 4 + grp;
                const int pslot = slot ^ (row & 7);
                aF[m] = *reinterpret_cast<const bf16x8*>(&As[row * 64 + pslot * 8]);
            }
#pragma unroll
            for (int n = 0; n < 4; ++n) {
                const int col = wc * 64 + n * 16 + c16;
                const int slot = j * 4 + grp;
                const int pslot = slot ^ (col & 7);
                bF[n] = *reinterpret_cast<const bf16x8*>(&Ws2[col * 64 + pslot * 8]);
            }
#pragma unroll
            for (int m = 0; m < 2; ++m)
#pragma unroll
                for (int n = 0; n < 4; ++n)
                    acc[m][n] = __builtin_amdgcn_mfma_f32_16x16x32_bf16(
                        aF[m], bF[n], acc[m][n], 0, 0, 0);
        }
    }

#pragma unroll
    for (int m = 0; m < 2; ++m) {
#pragma unroll
        for (int j = 0; j < 4; ++j) {
            const int row = wr * 32 + m * 16 + 4 * grp + j;
            float sm = 0.f, sq = 0.f;
#pragma unroll
            for (int n = 0; n < 4; ++n) {
                const int col = wc * 64 + n * 16 + c16;
                float v = acc[m][n][j] + bias[col]
                        + t[(size_t)(r0 + row) * D_ + col];
                acc[m][n][j] = v;
                sm += v;
                sq += v * v;
            }
#pragma unroll
            for (int off = 8; off >= 1; off >>= 1) {
                sm += __shfl_xor(sm, off);
                sq += __shfl_xor(sq, off);
            }
            if (c16 == 0) { red[row][wc][0] = sm; red[row][wc][1] = sq; }
        }
    }
    __syncthreads();

#pragma unroll
    for (int m = 0; m < 2; ++m) {
#pragma unroll
        for (int j = 0; j < 4; ++j) {
            const int row = wr * 32 + m * 16 + 4 * grp + j;
            const float sm = red[row][0][0] + red[row][1][0];
            const float sq = red[row][0][1] + red[row][1][1];
            const float mean = sm * (1.f / D_);
            const float var = sq * (1.f / D_) - mean * mean;
            const float rstd = rsqrtf(var + EPS_);
#pragma unroll
            for (int n = 0; n < 4; ++n) {
                const int col = wc * 64 + n * 16 + c16;
                const float o = (acc[m][n][j] - mean) * rstd * lng[col] + lnb[col];
                t[(size_t)(r0 + row) * D_ + col] = o;
                tb[(size_t)(r0 + row) * D_ + col] = f2bf(o);
            }
        }
    }
}

// ---------------------------------------------------------------------------
// Kernel 3: bf16-MFMA attention (r7 structure). r12: qkv input is bf16
// (pure-copy staging); Q-scale applied to fp32 scores; output bf16.
// ---------------------------------------------------------------------------
__global__ __launch_bounds__(256) void attn_mfma_kernel(
    const short* __restrict__ qkv, short* __restrict__ o)
{
    const int bh = blockIdx.x;
    const int b = bh >> 2;
    const int h = bh & 3;

    __shared__ short Qs[SP_ * 32];    // [i][c] bf16; rows 72..79 = 0
    __shared__ short Ks[SP_ * 32];    // [j][c] bf16; rows 72..79 = 0
    __shared__ short VT[32 * KP_];    // [c][j] bf16; j 72..95 = 0
    __shared__ short Pb[SP_ * KP_];   // [i][j] bf16 exp(s-mx); j 72..95 = 0

    const int tid = threadIdx.x;
    const int lane = tid & 63;
    const int wid = tid >> 6;         // 0..3
    const int g = lane >> 4;          // 0..3
    const int c16 = lane & 15;

    const float scale = 0.17677669529663687f;  // 1/sqrt(32)

    // --- stage Q, K as [row][c]; V transposed into VT[c][j] (pure copy)
    for (int idx = tid; idx < S_ * 4; idx += 256) {
        const int i = idx >> 2;
        const int c8 = (idx & 3) * 8;
        const size_t base = ((size_t)(b * S_ + i)) * 384 + h * 32 + c8;
        const bf16x8 q = *reinterpret_cast<const bf16x8*>(&qkv[base]);
        const bf16x8 k = *reinterpret_cast<const bf16x8*>(&qkv[base + 128]);
        const bf16x8 v = *reinterpret_cast<const bf16x8*>(&qkv[base + 256]);
        *reinterpret_cast<bf16x8*>(&Qs[i * 32 + c8]) = q;
        *reinterpret_cast<bf16x8*>(&Ks[i * 32 + c8]) = k;
#pragma unroll
        for (int j = 0; j < 8; ++j) VT[(c8 + j) * KP_ + i] = v[j];
    }
    for (int idx = tid; idx < 8 * 32; idx += 256) {   // Q/K rows 72..79
        Qs[S_ * 32 + idx] = 0;
        Ks[S_ * 32 + idx] = 0;
    }
    for (int idx = tid; idx < 32 * 24; idx += 256) {  // VT j = 72..95
        VT[(idx / 24) * KP_ + 72 + idx % 24] = 0;
    }
    for (int idx = tid; idx < SP_ * 24; idx += 256) { // Pb j = 72..95
        Pb[(idx / 24) * KP_ + 72 + idx % 24] = 0;
    }
    __syncthreads();

    float invr[2][4];
#pragma unroll
    for (int mi = 0; mi < 2; ++mi) {
        const int m = wid + 4 * mi;
        if (m <= 4) {
            const int rowb = m * 16;
            const bf16x8 aF = *reinterpret_cast<const bf16x8*>(
                &Qs[(rowb + c16) * 32 + 8 * g]);
            f32x4 sc[5];
#pragma unroll
            for (int n = 0; n < 5; ++n) {
                const bf16x8 bF = *reinterpret_cast<const bf16x8*>(
                    &Ks[(n * 16 + c16) * 32 + 8 * g]);
                f32x4 z = {};
                sc[n] = __builtin_amdgcn_mfma_f32_16x16x32_bf16(aF, bF, z, 0, 0, 0);
                sc[n] = sc[n] * scale;        // exact fp32 scale (was pre-round)
            }
#pragma unroll
            for (int j = 0; j < 4; ++j) {
                float mx = -1e30f;
#pragma unroll
                for (int n = 0; n < 5; ++n) {
                    const int col = n * 16 + c16;
                    if (col < S_) mx = fmaxf(mx, sc[n][j]);
                }
                mx = fmaxf(mx, __shfl_xor(mx, 1));
                mx = fmaxf(mx, __shfl_xor(mx, 2));
                mx = fmaxf(mx, __shfl_xor(mx, 4));
                mx = fmaxf(mx, __shfl_xor(mx, 8));
                float den = 0.f;
                float p[5];
#pragma unroll
                for (int n = 0; n < 5; ++n) {
                    const int col = n * 16 + c16;
                    p[n] = (col < S_) ? __expf(sc[n][j] - mx) : 0.f;
                    den += p[n];
                }
                den += __shfl_xor(den, 1);
                den += __shfl_xor(den, 2);
                den += __shfl_xor(den, 4);
                den += __shfl_xor(den, 8);
                invr[mi][j] = 1.f / den;
                const int row = rowb + 4 * g + j;
#pragma unroll
                for (int n = 0; n < 5; ++n)
                    Pb[row * KP_ + n * 16 + c16] = f2bf(p[n]);
            }
        }
    }
    __syncthreads();

#pragma unroll
    for (int mi = 0; mi < 2; ++mi) {
        const int m = wid + 4 * mi;
        if (m <= 4) {
            const int rowb = m * 16;
            f32x4 accO[2] = {};
#pragma unroll
            for (int kk = 0; kk < 3; ++kk) {
                const bf16x8 aF = *reinterpret_cast<const bf16x8*>(
                    &Pb[(rowb + c16) * KP_ + kk * 32 + 8 * g]);
#pragma unroll
                for (int n2 = 0; n2 < 2; ++n2) {
                    const bf16x8 bF = *reinterpret_cast<const bf16x8*>(
                        &VT[(n2 * 16 + c16) * KP_ + kk * 32 + 8 * g]);
                    accO[n2] = __builtin_amdgcn_mfma_f32_16x16x32_bf16(
                        aF, bF, accO[n2], 0, 0, 0);
                }
            }
#pragma unroll
            for (int j = 0; j < 4; ++j) {
                const int row = rowb + 4 * g + j;
                if (row < S_) {
                    const float inv = invr[mi][j];
#pragma unroll
                    for (int n2 = 0; n2 < 2; ++n2) {
                        o[((size_t)(b * S_ + row)) * D_ + h * 32 + n2 * 16 + c16]
                            = f2bf(accO[n2][j] * inv);
                    }
                }
            }
        }
    }
}

// ---------------------------------------------------------------------------
// Kernel 5: head MLP (fp32, reads t). One 64-thread block per (k, b).
// ---------------------------------------------------------------------------
__global__ __launch_bounds__(64) void head_kernel(
    const float* __restrict__ t, const float* __restrict__ h1_w,
    const float* __restrict__ h1_b, const float* __restrict__ h2_w,
    const float* __restrict__ h2_b, float* __restrict__ out)
{
    const int kb = blockIdx.x;
    const int k = kb / B_;
    const int b = kb - k * B_;
    const int o = threadIdx.x;  // 0..63

    const float* xr = &t[((size_t)(b * S_ + S_ - 1)) * D_];
    const float* wr = &h1_w[((size_t)k * 64 + o) * D_];
    float acc = h1_b[k * 64 + o];
#pragma unroll 8
    for (int d = 0; d < D_; ++d) acc = fmaf(xr[d], wr[d], acc);
    const float h1v = fmaxf(acc, 0.f);

#pragma unroll
    for (int p = 0; p < NS_; ++p) {
        float partial = h1v * h2_w[((size_t)k * NS_ + p) * 64 + o];
#pragma unroll
        for (int off = 32; off >= 1; off >>= 1) partial += __shfl_xor(partial, off);
        if (o == 0) out[((size_t)k * B_ + b) * NS_ + p] = partial + h2_b[k * NS_ + p];
    }
}

// ---------------------------------------------------------------------------
extern "C" void kernel_launch(void* const* d_in, const int* in_sizes, int n_in,
                              void* d_out, int out_size, void* d_ws, size_t ws_size,
                              hipStream_t stream) {
    const float* x        = (const float*)d_in[0];
    // d_in[1] = edge_index: graph is complete + self loops; structure hardcoded
    const float* gat_w    = (const float*)d_in[2];
    const float* att_src  = (const float*)d_in[3];
    const float* att_dst  = (const float*)d_in[4];
    const float* gat_bias = (const float*)d_in[5];
    const float* gat_ln_g = (const float*)d_in[6];
    const float* gat_ln_b = (const float*)d_in[7];
    const float* qkv_w    = (const float*)d_in[8];
    const float* qkv_b    = (const float*)d_in[9];
    const float* out_w    = (const float*)d_in[10];
    const float* out_b    = (const float*)d_in[11];
    const float* ln1_g    = (const float*)d_in[12];
    const float* ln1_b    = (const float*)d_in[13];
    const float* ff1_w    = (const float*)d_in[14];
    const float* ff1_b    = (const float*)d_in[15];
    const float* ff2_w    = (const float*)d_in[16];
    const float* ff2_b    = (const float*)d_in[17];
    const float* ln2_g    = (const float*)d_in[18];
    const float* ln2_b    = (const float*)d_in[19];
    const float* h1_w     = (const float*)d_in[20];
    const float* h1_b     = (const float*)d_in[21];
    const float* h2_w     = (const float*)d_in[22];
    const float* h2_b     = (const float*)d_in[23];
    float* out = (float*)d_out;

    // scratch layout (float units): t | qkvb | fbufb | tb | pe | gatc | wb
    float* base = (float*)d_ws;
    float* t     = base;               base += (size_t)G_ * D_;        // fp32
    short* qkvb  = (short*)base;       base += (size_t)G_ * 192;       // G*384 bf16
    short* fbufb = (short*)base;       base += (size_t)G_ * 128;       // G*256 bf16
    short* tb    = (short*)base;       base += (size_t)G_ * 64;        // G*128 bf16
    float* pe    = base;               base += (size_t)S_ * D_;
    float* gatc  = base;               base += 128;
    short* wb    = (short*)base;                                       // WTOT_ bf16

    pe_kernel<<<S_, 128, 0, stream>>>(pe);
    gatc_kernel<<<1, 128, 0, stream>>>(gat_w, att_src, att_dst, gatc);
    wcvt_kernel<<<WTOT_ / 1024, 256, 0, stream>>>(qkv_w, out_w, ff1_w, ff2_w, wb);
    gat_kernel<<<G_, 128, 0, stream>>>(x, gat_w, gatc,
                                       gat_bias, gat_ln_g, gat_ln_b, pe, t, tb);

    const short* wq = wb + WQKV_;
    const short* wo = wb + WOUT_;
    const short* w1 = wb + WFF1_;
    const short* w2 = wb + WFF2_;

    for (int l = 0; l < L_; ++l) {
        linear_mfma_kernel<<<dim3(G_ / 64, 384 / 64), 256, 0, stream>>>(
            tb, wq + (size_t)l * 384 * D_, qkv_b + (size_t)l * 384, qkvb,
            D_, 384, 0);
        attn_mfma_kernel<<<B_ * H_, 256, 0, stream>>>(qkvb, fbufb);
        // fused: t = LN(t + fbuf*out_w^T + out_b); emits tb
        linear_ln_kernel<<<G_ / 64, 256, 0, stream>>>(
            fbufb, wo + (size_t)l * D_ * D_, out_b + (size_t)l * D_, t, tb,
            ln1_g + l * D_, ln1_b + l * D_, D_);
        linear_mfma_kernel<<<dim3(G_ / 64, FF_ / 64), 256, 0, stream>>>(
            tb, w1 + (size_t)l * FF_ * D_, ff1_b + (size_t)l * FF_, fbufb,
            D_, FF_, 1);
        // fused: t = LN(t + fbuf*ff2_w^T + ff2_b); emits tb
        linear_ln_kernel<<<G_ / 64, 256, 0, stream>>>(
            fbufb, w2 + (size_t)l * D_ * FF_, ff2_b + (size_t)l * D_, t, tb,
            ln2_g + l * D_, ln2_b + l * D_, FF_);
    }

    head_kernel<<<K_ * B_, 64, 0, stream>>>(t, h1_w, h1_b, h2_w, h2_b, out);
}

// Round 15
// 393.780 us; speedup vs baseline: 1.3993x; 1.0629x over previous
//
#include <hip/hip_runtime.h>
#include <math.h>

// Problem constants
constexpr int B_ = 512, S_ = 72, N_ = 5, F_ = 10;
constexpr int H_ = 4, C_ = 32, D_ = 128;
constexpr int L_ = 3, FF_ = 256;
constexpr int K_ = 6, NS_ = 5;
constexpr int G_ = B_ * S_;           // 36864
constexpr float EPS_ = 1e-5f;
constexpr int SP_ = 80;               // S padded to 5*16 for MFMA fragments
constexpr int KP_ = 96;               // PV K-dim padded to 3*32

// bf16 weight arena offsets (shorts)
constexpr int WQKV_ = 0;                       // 3 * 384*128 = 147456
constexpr int WOUT_ = 147456;                  // 3 * 128*128 = 49152
constexpr int WFF1_ = 196608;                  // 3 * 256*128 = 98304
constexpr int WFF2_ = 294912;                  // 3 * 128*256 = 98304
constexpr int WTOT_ = 393216;

typedef short bf16x8 __attribute__((ext_vector_type(8)));
typedef float f32x4 __attribute__((ext_vector_type(4)));

__device__ __forceinline__ short f2bf(float f) {
    unsigned int u = __float_as_uint(f);
    u += 0x7FFFu + ((u >> 16) & 1u);      // round-to-nearest-even
    return (short)(u >> 16);
}

// ---------------------------------------------------------------------------
// Kernel 0a: positional-encoding table (S x D), once per launch.
// ---------------------------------------------------------------------------
__global__ __launch_bounds__(128) void pe_kernel(float* __restrict__ pe)
{
    const int s = blockIdx.x;           // 0..71
    const int d = threadIdx.x;          // 0..127
    const float expo = -(float)(d & ~1) * (9.210340371976184f / 128.f);
    const float ang = (float)s * expf(expo);
    pe[s * D_ + d] = (d & 1) ? cosf(ang) : sinf(ang);
}

// ---------------------------------------------------------------------------
// Kernel 0b: GAT attention-logit factorization tables (r10, HW-validated).
// ---------------------------------------------------------------------------
__global__ __launch_bounds__(128) void gatc_kernel(
    const float* __restrict__ gat_w, const float* __restrict__ att_src,
    const float* __restrict__ att_dst, float* __restrict__ gatc)
{
    const int t = threadIdx.x;
    if (t < 40) {
        const int f = t >> 2, h = t & 3;
        float s = 0.f;
#pragma unroll
        for (int c = 0; c < 32; ++c)
            s = fmaf(gat_w[f * D_ + h * 32 + c], att_src[h * 32 + c], s);
        gatc[t] = s;
    } else if (t < 80) {
        const int f = (t - 40) >> 2, h = (t - 40) & 3;
        float s = 0.f;
#pragma unroll
        for (int c = 0; c < 32; ++c)
            s = fmaf(gat_w[f * D_ + h * 32 + c], att_dst[h * 32 + c], s);
        gatc[t] = s;
    }
}

// ---------------------------------------------------------------------------
// Kernel 0c: convert ALL transformer weights fp32->bf16 ONCE per launch.
// ---------------------------------------------------------------------------
__global__ __launch_bounds__(256) void wcvt_kernel(
    const float* __restrict__ qw, const float* __restrict__ ow,
    const float* __restrict__ f1, const float* __restrict__ f2,
    short* __restrict__ wb)
{
    const int i4 = (blockIdx.x * 256 + threadIdx.x) * 4;
    const float* src; int off;
    if (i4 < WOUT_)      { src = qw; off = i4; }
    else if (i4 < WFF1_) { src = ow; off = i4 - WOUT_; }
    else if (i4 < WFF2_) { src = f1; off = i4 - WFF1_; }
    else                 { src = f2; off = i4 - WFF2_; }
    const float4 v = *reinterpret_cast<const float4*>(&src[off]);
    short4 h;
    h.x = f2bf(v.x); h.y = f2bf(v.y); h.z = f2bf(v.z); h.w = f2bf(v.w);
    *reinterpret_cast<short4*>(&wb[i4]) = h;
}

// ---------------------------------------------------------------------------
// Kernel 1: fused GAT -> layernorm -> node-mean -> +pe.
// r14: context-lane softmax. r13 profile: VALUBusy 86%, instruction-bound;
// ~225 of ~400 ops/thread computed values that are lane-redundant within a
// head (a_src/a_dst dots + 5-node softmax: 140 distinct values/group).
// Now: 40 lanes compute logits, 20 lanes softmax->alpha (LDS broadcast);
// all lanes do only d-dependent work (hn 50 FMA + agg 25 FMA).
// ---------------------------------------------------------------------------
__global__ __launch_bounds__(128) void gat_kernel(
    const float* __restrict__ x,        // (G, N, F)
    const float* __restrict__ gat_w,    // (F, D)
    const float* __restrict__ gatc,     // [wsrc(40)|wdst(40)]
    const float* __restrict__ gat_bias, // (D)
    const float* __restrict__ ln_g,     // (D)
    const float* __restrict__ ln_b,     // (D)
    const float* __restrict__ pe,       // (S, D)
    float* __restrict__ t_out,          // (G, D) fp32
    short* __restrict__ tb_out)         // (G, D) bf16
{
    const int g = blockIdx.x;
    const int d = threadIdx.x;          // 0..127
    const int s = g % S_;
    const int head = d >> 5;

    __shared__ float xs[N_][F_];
    __shared__ float ash[N_][H_];       // a_src[node][head]
    __shared__ float adh[N_][H_];       // a_dst[node][head]
    __shared__ float al[N_][N_][H_];    // alpha[dst][src][head]
    __shared__ float red[N_][2][2];     // [n][wave][sum, sumsq]

    if (d < N_ * F_) xs[d / F_][d % F_] = x[(size_t)g * N_ * F_ + d];
    __syncthreads();

    // Phase A: 40 context lanes compute per-(node,head) logit halves
    if (d < 40) {
        const int isdst = (d >= 20);
        const int idx = isdst ? d - 20 : d;
        const int n = idx >> 2, h = idx & 3;
        const float* wtab = gatc + (isdst ? 40 : 0);
        float acc = 0.f;
#pragma unroll
        for (int f = 0; f < F_; ++f)
            acc = fmaf(xs[n][f], wtab[f * 4 + h], acc);
        if (isdst) adh[n][h] = acc; else ash[n][h] = acc;
    }

    // d-dependent projection (overlaps Phase A across waves)
    float wcol[F_];
#pragma unroll
    for (int f = 0; f < F_; ++f) wcol[f] = gat_w[f * D_ + d];
    float hn[N_];
#pragma unroll
    for (int n = 0; n < N_; ++n) {
        float acc = 0.f;
#pragma unroll
        for (int f = 0; f < F_; ++f) acc = fmaf(xs[n][f], wcol[f], acc);
        hn[n] = acc;
    }
    __syncthreads();

    // Phase B: 20 context lanes do the 5-src softmax for (dst n, head h)
    if (d < 20) {
        const int n = d >> 2, h = d & 3;
        const float ad = adh[n][h];
        float e[N_];
        float mx = -1e30f;
#pragma unroll
        for (int m = 0; m < N_; ++m) {
            float v = ash[m][h] + ad;
            v = v > 0.f ? v : 0.2f * v;       // leaky_relu(0.2)
            e[m] = v;
            mx = fmaxf(mx, v);
        }
        float den = 0.f;
#pragma unroll
        for (int m = 0; m < N_; ++m) { e[m] = __expf(e[m] - mx); den += e[m]; }
        const float inv = 1.f / den;
#pragma unroll
        for (int m = 0; m < N_; ++m) al[n][m][h] = e[m] * inv;
    }
    __syncthreads();

    // Phase C: aggregate (alpha reads are LDS broadcasts per head group)
    const float bv = gat_bias[d];
    float y[N_];
#pragma unroll
    for (int n = 0; n < N_; ++n) {
        float agg = 0.f;
#pragma unroll
        for (int m = 0; m < N_; ++m) agg = fmaf(al[n][m][head], hn[m], agg);
        y[n] = agg + bv;
    }

    const int wave = d >> 6;
#pragma unroll
    for (int n = 0; n < N_; ++n) {
        float sm = y[n];
        float sq = y[n] * y[n];
#pragma unroll
        for (int off = 32; off >= 1; off >>= 1) {
            sm += __shfl_xor(sm, off);
            sq += __shfl_xor(sq, off);
        }
        if ((d & 63) == 0) { red[n][wave][0] = sm; red[n][wave][1] = sq; }
    }
    __syncthreads();

    const float gg = ln_g[d];
    const float bb = ln_b[d];
    float tacc = 0.f;
#pragma unroll
    for (int n = 0; n < N_; ++n) {
        const float sm = red[n][0][0] + red[n][1][0];
        const float sq = red[n][0][1] + red[n][1][1];
        const float mean = sm * (1.f / D_);
        const float var = sq * (1.f / D_) - mean * mean;
        const float rstd = rsqrtf(var + EPS_);
        tacc += (y[n] - mean) * rstd * gg + bb;
    }
    tacc *= (1.f / N_);

    const float val = tacc + pe[s * D_ + d];
    t_out[(size_t)g * D_ + d] = val;
    tb_out[(size_t)g * D_ + d] = f2bf(val);
}

// ---------------------------------------------------------------------------
// Kernel 2: bf16-MFMA linear: out_bf16 = act(A*W^T + bias).
// r14: 128x64 block tile (was 64x64). Wave tile 64 rows x 32 cols (4m x 2n
// fragments) -> 16 MFMA per K-step per wave (was 8); W staging per output
// halved. Same HW-validated fragment + swizzle pattern. LDS 24 KB.
// ---------------------------------------------------------------------------
__global__ __launch_bounds__(256) void linear_mfma_kernel(
    const short* __restrict__ A, const short* __restrict__ W,
    const float* __restrict__ bias, short* __restrict__ out,
    int K, int Cout, int relu)
{
    __shared__ short As[128 * 64];  // [row][k], 16KB
    __shared__ short Ws[64 * 64];   // [col][k], 8KB

    const int tid = threadIdx.x;
    const int lane = tid & 63;
    const int wid = tid >> 6;       // 0..3
    const int wr = wid >> 1;        // wave row block (0/1): 64 rows each
    const int wc = wid & 1;         // wave col block (0/1): 32 cols each
    const int r0 = blockIdx.x * 128;
    const int c0 = blockIdx.y * 64;

    const int st_row = tid >> 3;    // 0..31
    const int st_slot = tid & 7;    // k-slot (8 bf16 = 16B)

    f32x4 acc[4][2] = {};

    for (int kk = 0; kk < K; kk += 64) {
        if (kk) __syncthreads();
#pragma unroll
        for (int it = 0; it < 4; ++it) {       // A: 128 rows
            const int row = st_row + it * 32;
            const int gk = kk + st_slot * 8;
            const int pslot = st_slot ^ (row & 7);
            *reinterpret_cast<bf16x8*>(&As[row * 64 + pslot * 8]) =
                *reinterpret_cast<const bf16x8*>(&A[(size_t)(r0 + row) * K + gk]);
        }
#pragma unroll
        for (int it = 0; it < 2; ++it) {       // W: 64 cols
            const int row = st_row + it * 32;
            const int gk = kk + st_slot * 8;
            const int pslot = st_slot ^ (row & 7);
            *reinterpret_cast<bf16x8*>(&Ws[row * 64 + pslot * 8]) =
                *reinterpret_cast<const bf16x8*>(&W[(size_t)(c0 + row) * K + gk]);
        }
        __syncthreads();

#pragma unroll
        for (int j = 0; j < 2; ++j) {
            bf16x8 aF[4], bF[2];
#pragma unroll
            for (int m = 0; m < 4; ++m) {
                const int row = wr * 64 + m * 16 + (lane & 15);
                const int slot = j * 4 + (lane >> 4);
                const int pslot = slot ^ (row & 7);
                aF[m] = *reinterpret_cast<const bf16x8*>(&As[row * 64 + pslot * 8]);
            }
#pragma unroll
            for (int n = 0; n < 2; ++n) {
                const int col = wc * 32 + n * 16 + (lane & 15);
                const int slot = j * 4 + (lane >> 4);
                const int pslot = slot ^ (col & 7);
                bF[n] = *reinterpret_cast<const bf16x8*>(&Ws[col * 64 + pslot * 8]);
            }
#pragma unroll
            for (int m = 0; m < 4; ++m)
#pragma unroll
                for (int n = 0; n < 2; ++n)
                    acc[m][n] = __builtin_amdgcn_mfma_f32_16x16x32_bf16(
                        aF[m], bF[n], acc[m][n], 0, 0, 0);
        }
    }

#pragma unroll
    for (int m = 0; m < 4; ++m) {
#pragma unroll
        for (int n = 0; n < 2; ++n) {
            const int col = c0 + wc * 32 + n * 16 + (lane & 15);
            const float bv = bias[col];
#pragma unroll
            for (int j = 0; j < 4; ++j) {
                const int row = r0 + wr * 64 + m * 16 + (lane >> 4) * 4 + j;
                float v = acc[m][n][j] + bv;
                if (relu) v = fmaxf(v, 0.f);
                out[(size_t)row * Cout + col] = f2bf(v);
            }
        }
    }
}

// ---------------------------------------------------------------------------
// Kernel 2b: bf16-MFMA linear (Cout=128) fused residual-add + LayerNorm
// (r9/r12 structure, HW-validated): t = LN(t + A*W^T + bias); emits bf16 tb.
// ---------------------------------------------------------------------------
__global__ __launch_bounds__(256) void linear_ln_kernel(
    const short* __restrict__ A, const short* __restrict__ W,
    const float* __restrict__ bias, float* __restrict__ t,
    short* __restrict__ tb,
    const float* __restrict__ lng, const float* __restrict__ lnb,
    int K)
{
    __shared__ short As[64 * 64];    // 8KB
    __shared__ short Ws2[128 * 64];  // 16KB
    __shared__ float red[64][2][2];  // [row][wc][sum,sumsq], 1KB

    const int tid = threadIdx.x;
    const int lane = tid & 63;
    const int wid = tid >> 6;       // 0..3
    const int wr = wid >> 1;        // 0/1: rows 32*wr..
    const int wc = wid & 1;         // 0/1: cols 64*wc..
    const int c16 = lane & 15;
    const int grp = lane >> 4;      // 0..3
    const int r0 = blockIdx.x * 64;

    const int st_row = tid >> 3;    // 0..31
    const int st_slot = tid & 7;

    f32x4 acc[2][4] = {};

    for (int kk = 0; kk < K; kk += 64) {
        if (kk) __syncthreads();
#pragma unroll
        for (int it = 0; it < 2; ++it) {
            const int row = st_row + it * 32;
            const int gk = kk + st_slot * 8;
            const int pslot = st_slot ^ (row & 7);
            *reinterpret_cast<bf16x8*>(&As[row * 64 + pslot * 8]) =
                *reinterpret_cast<const bf16x8*>(&A[(size_t)(r0 + row) * K + gk]);
        }
#pragma unroll
        for (int it = 0; it < 4; ++it) {
            const int row = st_row + it * 32;
            const int gk = kk + st_slot * 8;
            const int pslot = st_slot ^ (row & 7);
            *reinterpret_cast<bf16x8*>(&Ws2[row * 64 + pslot * 8]) =
                *reinterpret_cast<const bf16x8*>(&W[(size_t)row * K + gk]);
        }
        __syncthreads();

#pragma unroll
        for (int j = 0; j < 2; ++j) {
            bf16x8 aF[2], bF[4];
#pragma unroll
            for (int m = 0; m < 2; ++m) {
                const int row = wr * 32 + m * 16 + c16;
                const int slot = j * 4 + grp;
                const int pslot = slot ^ (row & 7);
                aF[m] = *reinterpret_cast<const bf16x8*>(&As[row * 64 + pslot * 8]);
            }
#pragma unroll
            for (int n = 0; n < 4; ++n) {
                const int col = wc * 64 + n * 16 + c16;
                const int slot = j * 4 + grp;
                const int pslot = slot ^ (col & 7);
                bF[n] = *reinterpret_cast<const bf16x8*>(&Ws2[col * 64 + pslot * 8]);
            }
#pragma unroll
            for (int m = 0; m < 2; ++m)
#pragma unroll
                for (int n = 0; n < 4; ++n)
                    acc[m][n] = __builtin_amdgcn_mfma_f32_16x16x32_bf16(
                        aF[m], bF[n], acc[m][n], 0, 0, 0);
        }
    }

#pragma unroll
    for (int m = 0; m < 2; ++m) {
#pragma unroll
        for (int j = 0; j < 4; ++j) {
            const int row = wr * 32 + m * 16 + 4 * grp + j;
            float sm = 0.f, sq = 0.f;
#pragma unroll
            for (int n = 0; n < 4; ++n) {
                const int col = wc * 64 + n * 16 + c16;
                float v = acc[m][n][j] + bias[col]
                        + t[(size_t)(r0 + row) * D_ + col];
                acc[m][n][j] = v;
                sm += v;
                sq += v * v;
            }
#pragma unroll
            for (int off = 8; off >= 1; off >>= 1) {
                sm += __shfl_xor(sm, off);
                sq += __shfl_xor(sq, off);
            }
            if (c16 == 0) { red[row][wc][0] = sm; red[row][wc][1] = sq; }
        }
    }
    __syncthreads();

#pragma unroll
    for (int m = 0; m < 2; ++m) {
#pragma unroll
        for (int j = 0; j < 4; ++j) {
            const int row = wr * 32 + m * 16 + 4 * grp + j;
            const float sm = red[row][0][0] + red[row][1][0];
            const float sq = red[row][0][1] + red[row][1][1];
            const float mean = sm * (1.f / D_);
            const float var = sq * (1.f / D_) - mean * mean;
            const float rstd = rsqrtf(var + EPS_);
#pragma unroll
            for (int n = 0; n < 4; ++n) {
                const int col = wc * 64 + n * 16 + c16;
                const float o = (acc[m][n][j] - mean) * rstd * lng[col] + lnb[col];
                t[(size_t)(r0 + row) * D_ + col] = o;
                tb[(size_t)(r0 + row) * D_ + col] = f2bf(o);
            }
        }
    }
}

// ---------------------------------------------------------------------------
// Kernel 3: bf16-MFMA attention (r7/r12 structure, HW-validated).
// ---------------------------------------------------------------------------
__global__ __launch_bounds__(256) void attn_mfma_kernel(
    const short* __restrict__ qkv, short* __restrict__ o)
{
    const int bh = blockIdx.x;
    const int b = bh >> 2;
    const int h = bh & 3;

    __shared__ short Qs[SP_ * 32];    // [i][c] bf16; rows 72..79 = 0
    __shared__ short Ks[SP_ * 32];    // [j][c] bf16; rows 72..79 = 0
    __shared__ short VT[32 * KP_];    // [c][j] bf16; j 72..95 = 0
    __shared__ short Pb[SP_ * KP_];   // [i][j] bf16 exp(s-mx); j 72..95 = 0

    const int tid = threadIdx.x;
    const int lane = tid & 63;
    const int wid = tid >> 6;         // 0..3
    const int g = lane >> 4;          // 0..3
    const int c16 = lane & 15;

    const float scale = 0.17677669529663687f;  // 1/sqrt(32)

    for (int idx = tid; idx < S_ * 4; idx += 256) {
        const int i = idx >> 2;
        const int c8 = (idx & 3) * 8;
        const size_t base = ((size_t)(b * S_ + i)) * 384 + h * 32 + c8;
        const bf16x8 q = *reinterpret_cast<const bf16x8*>(&qkv[base]);
        const bf16x8 k = *reinterpret_cast<const bf16x8*>(&qkv[base + 128]);
        const bf16x8 v = *reinterpret_cast<const bf16x8*>(&qkv[base + 256]);
        *reinterpret_cast<bf16x8*>(&Qs[i * 32 + c8]) = q;
        *reinterpret_cast<bf16x8*>(&Ks[i * 32 + c8]) = k;
#pragma unroll
        for (int j = 0; j < 8; ++j) VT[(c8 + j) * KP_ + i] = v[j];
    }
    for (int idx = tid; idx < 8 * 32; idx += 256) {   // Q/K rows 72..79
        Qs[S_ * 32 + idx] = 0;
        Ks[S_ * 32 + idx] = 0;
    }
    for (int idx = tid; idx < 32 * 24; idx += 256) {  // VT j = 72..95
        VT[(idx / 24) * KP_ + 72 + idx % 24] = 0;
    }
    for (int idx = tid; idx < SP_ * 24; idx += 256) { // Pb j = 72..95
        Pb[(idx / 24) * KP_ + 72 + idx % 24] = 0;
    }
    __syncthreads();

    float invr[2][4];
#pragma unroll
    for (int mi = 0; mi < 2; ++mi) {
        const int m = wid + 4 * mi;
        if (m <= 4) {
            const int rowb = m * 16;
            const bf16x8 aF = *reinterpret_cast<const bf16x8*>(
                &Qs[(rowb + c16) * 32 + 8 * g]);
            f32x4 sc[5];
#pragma unroll
            for (int n = 0; n < 5; ++n) {
                const bf16x8 bF = *reinterpret_cast<const bf16x8*>(
                    &Ks[(n * 16 + c16) * 32 + 8 * g]);
                f32x4 z = {};
                sc[n] = __builtin_amdgcn_mfma_f32_16x16x32_bf16(aF, bF, z, 0, 0, 0);
                sc[n] = sc[n] * scale;        // exact fp32 scale
            }
#pragma unroll
            for (int j = 0; j < 4; ++j) {
                float mx = -1e30f;
#pragma unroll
                for (int n = 0; n < 5; ++n) {
                    const int col = n * 16 + c16;
                    if (col < S_) mx = fmaxf(mx, sc[n][j]);
                }
                mx = fmaxf(mx, __shfl_xor(mx, 1));
                mx = fmaxf(mx, __shfl_xor(mx, 2));
                mx = fmaxf(mx, __shfl_xor(mx, 4));
                mx = fmaxf(mx, __shfl_xor(mx, 8));
                float den = 0.f;
                float p[5];
#pragma unroll
                for (int n = 0; n < 5; ++n) {
                    const int col = n * 16 + c16;
                    p[n] = (col < S_) ? __expf(sc[n][j] - mx) : 0.f;
                    den += p[n];
                }
                den += __shfl_xor(den, 1);
                den += __shfl_xor(den, 2);
                den += __shfl_xor(den, 4);
                den += __shfl_xor(den, 8);
                invr[mi][j] = 1.f / den;
                const int row = rowb + 4 * g + j;
#pragma unroll
                for (int n = 0; n < 5; ++n)
                    Pb[row * KP_ + n * 16 + c16] = f2bf(p[n]);
            }
        }
    }
    __syncthreads();

#pragma unroll
    for (int mi = 0; mi < 2; ++mi) {
        const int m = wid + 4 * mi;
        if (m <= 4) {
            const int rowb = m * 16;
            f32x4 accO[2] = {};
#pragma unroll
            for (int kk = 0; kk < 3; ++kk) {
                const bf16x8 aF = *reinterpret_cast<const bf16x8*>(
                    &Pb[(rowb + c16) * KP_ + kk * 32 + 8 * g]);
#pragma unroll
                for (int n2 = 0; n2 < 2; ++n2) {
                    const bf16x8 bF = *reinterpret_cast<const bf16x8*>(
                        &VT[(n2 * 16 + c16) * KP_ + kk * 32 + 8 * g]);
                    accO[n2] = __builtin_amdgcn_mfma_f32_16x16x32_bf16(
                        aF, bF, accO[n2], 0, 0, 0);
                }
            }
#pragma unroll
            for (int j = 0; j < 4; ++j) {
                const int row = rowb + 4 * g + j;
                if (row < S_) {
                    const float inv = invr[mi][j];
#pragma unroll
                    for (int n2 = 0; n2 < 2; ++n2) {
                        o[((size_t)(b * S_ + row)) * D_ + h * 32 + n2 * 16 + c16]
                            = f2bf(accO[n2][j] * inv);
                    }
                }
            }
        }
    }
}

// ---------------------------------------------------------------------------
// Kernel 5: head MLP (fp32, reads t). One 64-thread block per (k, b).
// ---------------------------------------------------------------------------
__global__ __launch_bounds__(64) void head_kernel(
    const float* __restrict__ t, const float* __restrict__ h1_w,
    const float* __restrict__ h1_b, const float* __restrict__ h2_w,
    const float* __restrict__ h2_b, float* __restrict__ out)
{
    const int kb = blockIdx.x;
    const int k = kb / B_;
    const int b = kb - k * B_;
    const int o = threadIdx.x;  // 0..63

    const float* xr = &t[((size_t)(b * S_ + S_ - 1)) * D_];
    const float* wr = &h1_w[((size_t)k * 64 + o) * D_];
    float acc = h1_b[k * 64 + o];
#pragma unroll 8
    for (int d = 0; d < D_; ++d) acc = fmaf(xr[d], wr[d], acc);
    const float h1v = fmaxf(acc, 0.f);

#pragma unroll
    for (int p = 0; p < NS_; ++p) {
        float partial = h1v * h2_w[((size_t)k * NS_ + p) * 64 + o];
#pragma unroll
        for (int off = 32; off >= 1; off >>= 1) partial += __shfl_xor(partial, off);
        if (o == 0) out[((size_t)k * B_ + b) * NS_ + p] = partial + h2_b[k * NS_ + p];
    }
}

// ---------------------------------------------------------------------------
extern "C" void kernel_launch(void* const* d_in, const int* in_sizes, int n_in,
                              void* d_out, int out_size, void* d_ws, size_t ws_size,
                              hipStream_t stream) {
    const float* x        = (const float*)d_in[0];
    // d_in[1] = edge_index: graph is complete + self loops; structure hardcoded
    const float* gat_w    = (const float*)d_in[2];
    const float* att_src  = (const float*)d_in[3];
    const float* att_dst  = (const float*)d_in[4];
    const float* gat_bias = (const float*)d_in[5];
    const float* gat_ln_g = (const float*)d_in[6];
    const float* gat_ln_b = (const float*)d_in[7];
    const float* qkv_w    = (const float*)d_in[8];
    const float* qkv_b    = (const float*)d_in[9];
    const float* out_w    = (const float*)d_in[10];
    const float* out_b    = (const float*)d_in[11];
    const float* ln1_g    = (const float*)d_in[12];
    const float* ln1_b    = (const float*)d_in[13];
    const float* ff1_w    = (const float*)d_in[14];
    const float* ff1_b    = (const float*)d_in[15];
    const float* ff2_w    = (const float*)d_in[16];
    const float* ff2_b    = (const float*)d_in[17];
    const float* ln2_g    = (const float*)d_in[18];
    const float* ln2_b    = (const float*)d_in[19];
    const float* h1_w     = (const float*)d_in[20];
    const float* h1_b     = (const float*)d_in[21];
    const float* h2_w     = (const float*)d_in[22];
    const float* h2_b     = (const float*)d_in[23];
    float* out = (float*)d_out;

    // scratch layout (float units): t | qkvb | fbufb | tb | pe | gatc | wb
    float* base = (float*)d_ws;
    float* t     = base;               base += (size_t)G_ * D_;        // fp32
    short* qkvb  = (short*)base;       base += (size_t)G_ * 192;       // G*384 bf16
    short* fbufb = (short*)base;       base += (size_t)G_ * 128;       // G*256 bf16
    short* tb    = (short*)base;       base += (size_t)G_ * 64;        // G*128 bf16
    float* pe    = base;               base += (size_t)S_ * D_;
    float* gatc  = base;               base += 128;
    short* wb    = (short*)base;                                       // WTOT_ bf16

    pe_kernel<<<S_, 128, 0, stream>>>(pe);
    gatc_kernel<<<1, 128, 0, stream>>>(gat_w, att_src, att_dst, gatc);
    wcvt_kernel<<<WTOT_ / 1024, 256, 0, stream>>>(qkv_w, out_w, ff1_w, ff2_w, wb);
    gat_kernel<<<G_, 128, 0, stream>>>(x, gat_w, gatc,
                                       gat_bias, gat_ln_g, gat_ln_b, pe, t, tb);

    const short* wq = wb + WQKV_;
    const short* wo = wb + WOUT_;
    const short* w1 = wb + WFF1_;
    const short* w2 = wb + WFF2_;

    for (int l = 0; l < L_; ++l) {
        linear_mfma_kernel<<<dim3(G_ / 128, 384 / 64), 256, 0, stream>>>(
            tb, wq + (size_t)l * 384 * D_, qkv_b + (size_t)l * 384, qkvb,
            D_, 384, 0);
        attn_mfma_kernel<<<B_ * H_, 256, 0, stream>>>(qkvb, fbufb);
        // fused: t = LN(t + fbuf*out_w^T + out_b); emits tb
        linear_ln_kernel<<<G_ / 64, 256, 0, stream>>>(
            fbufb, wo + (size_t)l * D_ * D_, out_b + (size_t)l * D_, t, tb,
            ln1_g + l * D_, ln1_b + l * D_, D_);
        linear_mfma_kernel<<<dim3(G_ / 128, FF_ / 64), 256, 0, stream>>>(
            tb, w1 + (size_t)l * FF_ * D_, ff1_b + (size_t)l * FF_, fbufb,
            D_, FF_, 1);
        // fused: t = LN(t + fbuf*ff2_w^T + ff2_b); emits tb
        linear_ln_kernel<<<G_ / 64, 256, 0, stream>>>(
            fbufb, w2 + (size_t)l * D_ * FF_, ff2_b + (size_t)l * D_, t, tb,
            ln2_g + l * D_, ln2_b + l * D_, FF_);
    }

    head_kernel<<<K_ * B_, 64, 0, stream>>>(t, h1_w, h1_b, h2_w, h2_b, out);
}